// Round 1
// baseline (1796.198 us; speedup 1.0000x reference)
//
#include <hip/hip_runtime.h>
#include <math.h>

// Problem constants (from reference setup_inputs)
#define N_ROWS 262144
#define DX 64
#define DZ 32
#define NB 1024
#define NBF 262144.0f
#define MIN_ASSIGN (0.1f / 1024.0f)

// Workspace layout (float offsets)
#define WS_RECON  0
#define WS_COMMIT 1
#define WS_COUNTS 64
#define WS_SUMZ   1088            // 64 + 1024
#define WS_VNORM  33856           // 1088 + 32768
#define WS_MUTAB  34880           // 33856 + 1024
#define WS_ZERO_N 33856           // zero recon/commit/counts/sum_z

__global__ __launch_bounds__(256) void zero_kernel(float* __restrict__ p, int n) {
    int i = blockIdx.x * 256 + threadIdx.x;
    if (i < n) p[i] = 0.0f;
}

// Per-bin: vnorm[j] = ||vectors[j]||^2 ; mu_table[j] = vectors[j] @ W_dec + b_dec
__global__ __launch_bounds__(64) void vq_prep(
    const float* __restrict__ vectors, const float* __restrict__ W_dec,
    const float* __restrict__ b_dec, float* __restrict__ vnorm,
    float* __restrict__ mu_table)
{
    const int j = blockIdx.x;
    const int t = threadIdx.x;
    __shared__ float v[DZ];
    if (t < DZ) v[t] = vectors[j * DZ + t];
    __syncthreads();
    float m = b_dec[t];
    #pragma unroll
    for (int k = 0; k < DZ; ++k) m = fmaf(v[k], W_dec[k * DX + t], m);
    mu_table[(size_t)j * DX + t] = m;
    if (t == 0) {
        float s = 0.0f;
        #pragma unroll
        for (int k = 0; k < DZ; ++k) s = fmaf(v[k], v[k], s);
        vnorm[j] = s;
    }
}

__global__ __launch_bounds__(256) void vq_main(
    const float* __restrict__ x, const float* __restrict__ W_enc,
    const float* __restrict__ b_enc, const float* __restrict__ vectors,
    const float* __restrict__ vnorm, const float* __restrict__ mu_table,
    float* __restrict__ counts, float* __restrict__ sum_z,
    float* __restrict__ recon_acc, float* __restrict__ commit_acc)
{
    const int r = blockIdx.x * 256 + threadIdx.x;

    // ---- load x row (coalesced float4 within-thread; 64 regs) ----
    float xr[DX];
    const float4* xp = reinterpret_cast<const float4*>(x + (size_t)r * DX);
    #pragma unroll
    for (int i = 0; i < DX / 4; ++i) {
        float4 v = xp[i];
        xr[4 * i + 0] = v.x; xr[4 * i + 1] = v.y;
        xr[4 * i + 2] = v.z; xr[4 * i + 3] = v.w;
    }

    // ---- encoder: z = x @ W_enc + b_enc (W_enc reads are wave-uniform -> s_load) ----
    float z[DZ];
    #pragma unroll
    for (int c = 0; c < DZ; ++c) z[c] = b_enc[c];
    #pragma unroll
    for (int k = 0; k < DX; ++k) {
        float xk = xr[k];
        #pragma unroll
        for (int c = 0; c < DZ; ++c) z[c] = fmaf(xk, W_enc[k * DZ + c], z[c]);
    }

    float znorm = 0.0f;
    #pragma unroll
    for (int c = 0; c < DZ; ++c) znorm = fmaf(z[c], z[c], znorm);
    // pre-scale by -2 so the argmin inner loop is a single fmac per element
    float zm2[DZ];
    #pragma unroll
    for (int c = 0; c < DZ; ++c) zm2[c] = -2.0f * z[c];

    // ---- argmin over 1024 codes: score = vnorm[j] - 2*z.v[j] (znorm is a constant offset) ----
    float best = 3.4e38f;
    int bidx = 0;
    for (int j = 0; j < NB; ++j) {
        const float* vj = vectors + j * DZ;   // wave-uniform address -> scalar loads
        float s0 = vnorm[j], s1 = 0.0f, s2 = 0.0f, s3 = 0.0f;
        #pragma unroll
        for (int c = 0; c < DZ; c += 4) {
            s0 = fmaf(zm2[c + 0], vj[c + 0], s0);
            s1 = fmaf(zm2[c + 1], vj[c + 1], s1);
            s2 = fmaf(zm2[c + 2], vj[c + 2], s2);
            s3 = fmaf(zm2[c + 3], vj[c + 3], s3);
        }
        float s = (s0 + s1) + (s2 + s3);
        if (s < best) { best = s; bidx = j; }   // strict < keeps first index (argmin tie rule)
    }
    float commit_row = znorm + best;            // == ||z - quantized||^2

    // ---- reconstruction: ||x - mu_table[bidx]||^2 (scattered gather, L2-resident 256 KiB) ----
    float rs = 0.0f;
    const float4* mup = reinterpret_cast<const float4*>(mu_table + (size_t)bidx * DX);
    #pragma unroll
    for (int i = 0; i < DX / 4; ++i) {
        float4 m = mup[i];
        float d0 = xr[4 * i + 0] - m.x; rs = fmaf(d0, d0, rs);
        float d1 = xr[4 * i + 1] - m.y; rs = fmaf(d1, d1, rs);
        float d2 = xr[4 * i + 2] - m.z; rs = fmaf(d2, d2, rs);
        float d3 = xr[4 * i + 3] - m.w; rs = fmaf(d3, d3, rs);
    }

    // ---- per-bin accumulators ----
    atomicAdd(&counts[bidx], 1.0f);
    #pragma unroll
    for (int c = 0; c < DZ; ++c)
        atomicAdd(&sum_z[(size_t)bidx * DZ + c], -0.5f * zm2[c]);

    // ---- wave-reduce the two scalars, one atomic per wave ----
    #pragma unroll
    for (int off = 32; off > 0; off >>= 1) {
        rs += __shfl_down(rs, off, 64);
        commit_row += __shfl_down(commit_row, off, 64);
    }
    if ((threadIdx.x & 63) == 0) {
        atomicAdd(recon_acc, rs);
        atomicAdd(commit_acc, commit_row);
    }
}

__global__ __launch_bounds__(1024) void vq_finalize(
    const float* __restrict__ vectors, const float* __restrict__ assignments,
    const float* __restrict__ noise, const float* __restrict__ counts,
    const float* __restrict__ sum_z, const float* __restrict__ recon_acc,
    const float* __restrict__ commit_acc, float* __restrict__ out)
{
    __shared__ float a[NB];
    __shared__ unsigned char na[NB];
    __shared__ float rv[NB];
    __shared__ int ri[NB];
    __shared__ int s_max_idx;
    const int t = threadIdx.x;

    const float cnt = counts[t];
    const float ba = cnt / NBF;                 // batch_assign; ba*N == cnt exactly (N = 2^18)
    const float ae = 0.99f * assignments[t] + 0.01f * ba;
    a[t] = ae;
    na[t] = (ae * NBF < MIN_ASSIGN) ? 1 : 0;    // computed from pre-scan assign_ema, like reference
    rv[t] = ba; ri[t] = t;
    __syncthreads();

    // argmax(batch_assign), first occurrence on ties
    for (int s = NB / 2; s > 0; s >>= 1) {
        if (t < s) {
            float ov = rv[t + s]; int oi = ri[t + s];
            if (ov > rv[t] || (ov == rv[t] && oi < ri[t])) { rv[t] = ov; ri[t] = oi; }
        }
        __syncthreads();
    }
    if (t == 0) s_max_idx = ri[0];
    __syncthreads();
    const int mx = s_max_idx;

    // sequential dead-code scan, i = NB-1 .. 0 (reference iterates high->low)
    if (t == 0) {
        for (int i = NB - 1; i >= 0; --i) {
            if (na[i]) {
                float v = 0.5f * a[mx];
                a[i] = v;
                a[mx] = v;
            }
        }
    }
    __syncthreads();

    // assign_ema output (post-scan)
    out[1 + NB * DZ + t] = a[t];

    // new_vectors = 0.99*vecs2 + 0.01*mean_vector
    const bool dead = (na[t] != 0);
    #pragma unroll
    for (int c = 0; c < DZ; ++c) {
        float v2 = dead ? (vectors[mx * DZ + c] + noise[t * DZ + c])
                        : vectors[t * DZ + c];
        float mean = (cnt == 0.0f) ? v2 : (sum_z[(size_t)t * DZ + c] / cnt);
        out[1 + t * DZ + c] = 0.99f * v2 + 0.01f * mean;
    }

    if (t == 0) {
        // recon = 0.5*mean(||x-mu||^2) + 32*log(2*pi); loss = recon + 0.25*commit_mean
        float recon = 0.5f * (recon_acc[0] / NBF) + 32.0f * 1.8378770664093453f;
        float commit = commit_acc[0] / (NBF * (float)DZ);
        out[0] = recon + 0.25f * commit;
    }
}

extern "C" void kernel_launch(void* const* d_in, const int* in_sizes, int n_in,
                              void* d_out, int out_size, void* d_ws, size_t ws_size,
                              hipStream_t stream)
{
    const float* x           = (const float*)d_in[0];
    const float* W_enc       = (const float*)d_in[1];
    const float* b_enc       = (const float*)d_in[2];
    const float* vectors     = (const float*)d_in[3];
    const float* W_dec       = (const float*)d_in[4];
    const float* b_dec       = (const float*)d_in[5];
    const float* assignments = (const float*)d_in[6];
    const float* noise       = (const float*)d_in[7];
    float* out = (float*)d_out;
    float* ws  = (float*)d_ws;

    zero_kernel<<<(WS_ZERO_N + 255) / 256, 256, 0, stream>>>(ws, WS_ZERO_N);
    vq_prep<<<NB, 64, 0, stream>>>(vectors, W_dec, b_dec, ws + WS_VNORM, ws + WS_MUTAB);
    vq_main<<<N_ROWS / 256, 256, 0, stream>>>(x, W_enc, b_enc, vectors,
        ws + WS_VNORM, ws + WS_MUTAB, ws + WS_COUNTS, ws + WS_SUMZ,
        ws + WS_RECON, ws + WS_COMMIT);
    vq_finalize<<<1, NB, 0, stream>>>(vectors, assignments, noise,
        ws + WS_COUNTS, ws + WS_SUMZ, ws + WS_RECON, ws + WS_COMMIT, out);
}

// Round 2
// 682.009 us; speedup vs baseline: 2.6337x; 2.6337x over previous
//
#include <hip/hip_runtime.h>
#include <math.h>

// Problem constants (from reference setup_inputs)
#define N_ROWS 262144
#define DX 64
#define DZ 32
#define NB 1024
#define NBF 262144.0f
#define MIN_ASSIGN (0.1f / 1024.0f)

// ---------- fast-path workspace layout (float offsets) ----------
#define WS_RECON   0
#define WS_COMMIT  1
#define WS_VNORM   64
#define WS_MUTAB   1088                    // + 1024*64 = 65536
#define WS_ZT      66624                   // + 32*262144 = 8388608  (z transposed [c][r])
#define WS_BIDX    8455232                 // + 262144 (int32)
#define WS_HPART   8717376                 // + HCHUNKS*33*1024 = 1081344
#define WS_COUNTS  9798720                 // + 1024
#define WS_SUMZ    9799744                 // + 32768
#define WS_TOTAL   9832512                 // floats (~37.5 MB)
#define HCHUNKS 32
#define HROWS  (N_ROWS / HCHUNKS)          // 8192 rows per chunk

// ---------- fallback (round-1) workspace layout ----------
#define FB_RECON  0
#define FB_COMMIT 1
#define FB_COUNTS 64
#define FB_SUMZ   1088
#define FB_VNORM  33856
#define FB_MUTAB  34880
#define FB_ZERO_N 33856

__global__ __launch_bounds__(256) void zero_kernel(float* __restrict__ p, int n) {
    int i = blockIdx.x * 256 + threadIdx.x;
    if (i < n) p[i] = 0.0f;
}

// Per-bin: vnorm[j] = ||vectors[j]||^2 ; mu_table[j] = vectors[j] @ W_dec + b_dec
__global__ __launch_bounds__(64) void vq_prep(
    const float* __restrict__ vectors, const float* __restrict__ W_dec,
    const float* __restrict__ b_dec, float* __restrict__ vnorm,
    float* __restrict__ mu_table)
{
    const int j = blockIdx.x;
    const int t = threadIdx.x;
    __shared__ float v[DZ];
    if (t < DZ) v[t] = vectors[j * DZ + t];
    __syncthreads();
    float m = b_dec[t];
    #pragma unroll
    for (int k = 0; k < DZ; ++k) m = fmaf(v[k], W_dec[k * DX + t], m);
    mu_table[(size_t)j * DX + t] = m;
    if (t == 0) {
        float s = 0.0f;
        #pragma unroll
        for (int k = 0; k < DZ; ++k) s = fmaf(v[k], v[k], s);
        vnorm[j] = s;
    }
}

// ---------- fast path ----------

// Encoder: z = x @ W_enc + b_enc, stored transposed zT[c*N + r] (coalesced).
// Op order matches round-1 encoder exactly -> bit-identical z.
__global__ __launch_bounds__(256) void vq_enc(
    const float* __restrict__ x, const float* __restrict__ W_enc,
    const float* __restrict__ b_enc, float* __restrict__ zT)
{
    const int r = blockIdx.x * 256 + threadIdx.x;
    float xr[DX];
    const float4* xp = reinterpret_cast<const float4*>(x + (size_t)r * DX);
    #pragma unroll
    for (int i = 0; i < DX / 4; ++i) {
        float4 v = xp[i];
        xr[4 * i + 0] = v.x; xr[4 * i + 1] = v.y;
        xr[4 * i + 2] = v.z; xr[4 * i + 3] = v.w;
    }
    float z[DZ];
    #pragma unroll
    for (int c = 0; c < DZ; ++c) z[c] = b_enc[c];
    #pragma unroll
    for (int k = 0; k < DX; ++k) {
        float xk = xr[k];
        #pragma unroll
        for (int c = 0; c < DZ; ++c) z[c] = fmaf(xk, W_enc[k * DZ + c], z[c]);
    }
    #pragma unroll
    for (int c = 0; c < DZ; ++c) zT[(size_t)c * N_ROWS + r] = z[c];
}

// Argmin over 1024 codes + fused reconstruction. j-loop math is bit-identical
// to round 1 (which passed with absmax 0) -> same bidx per row.
__global__ __launch_bounds__(256) void vq_argmin(
    const float* __restrict__ zT, const float* __restrict__ vectors,
    const float* __restrict__ vnorm, const float* __restrict__ mu_table,
    const float* __restrict__ x, int* __restrict__ bidx_out,
    float* __restrict__ recon_acc, float* __restrict__ commit_acc)
{
    const int r = blockIdx.x * 256 + threadIdx.x;

    float z[DZ];
    #pragma unroll
    for (int c = 0; c < DZ; ++c) z[c] = zT[(size_t)c * N_ROWS + r];

    float znorm = 0.0f;
    #pragma unroll
    for (int c = 0; c < DZ; ++c) znorm = fmaf(z[c], z[c], znorm);
    float zm2[DZ];
    #pragma unroll
    for (int c = 0; c < DZ; ++c) zm2[c] = -2.0f * z[c];

    float best = 3.4e38f;
    int bidx = 0;
    for (int j = 0; j < NB; ++j) {
        const float* vj = vectors + j * DZ;   // wave-uniform -> s_load
        float s0 = vnorm[j], s1 = 0.0f, s2 = 0.0f, s3 = 0.0f;
        #pragma unroll
        for (int c = 0; c < DZ; c += 4) {
            s0 = fmaf(zm2[c + 0], vj[c + 0], s0);
            s1 = fmaf(zm2[c + 1], vj[c + 1], s1);
            s2 = fmaf(zm2[c + 2], vj[c + 2], s2);
            s3 = fmaf(zm2[c + 3], vj[c + 3], s3);
        }
        float s = (s0 + s1) + (s2 + s3);
        if (s < best) { best = s; bidx = j; }   // strict < == argmin first-index rule
    }
    bidx_out[r] = bidx;
    float commit_row = znorm + best;            // == ||z - quantized||^2

    // reconstruction: ||x - mu_table[bidx]||^2
    float rs = 0.0f;
    const float4* xp  = reinterpret_cast<const float4*>(x + (size_t)r * DX);
    const float4* mup = reinterpret_cast<const float4*>(mu_table + (size_t)bidx * DX);
    #pragma unroll
    for (int i = 0; i < DX / 4; ++i) {
        float4 xv = xp[i];
        float4 m  = mup[i];
        float d0 = xv.x - m.x; rs = fmaf(d0, d0, rs);
        float d1 = xv.y - m.y; rs = fmaf(d1, d1, rs);
        float d2 = xv.z - m.z; rs = fmaf(d2, d2, rs);
        float d3 = xv.w - m.w; rs = fmaf(d3, d3, rs);
    }

    // wave-reduce scalars, one atomic per wave (1024 waves total)
    #pragma unroll
    for (int off = 32; off > 0; off >>= 1) {
        rs += __shfl_down(rs, off, 64);
        commit_row += __shfl_down(commit_row, off, 64);
    }
    if ((threadIdx.x & 63) == 0) {
        atomicAdd(recon_acc, rs);
        atomicAdd(commit_acc, commit_row);
    }
}

// Component-sliced LDS histogram: block (c, chunk); c<32 sums zT[c], c==32 counts.
// Only LDS atomics; flush is plain coalesced writes to per-block partials.
__global__ __launch_bounds__(256) void vq_hist(
    const float* __restrict__ zT, const int* __restrict__ bidx,
    float* __restrict__ hpart)
{
    const int c     = blockIdx.x % 33;
    const int chunk = blockIdx.x / 33;
    const int t = threadIdx.x;
    __shared__ float h[NB];
    #pragma unroll
    for (int i = 0; i < NB / 256; ++i) h[t + 256 * i] = 0.0f;
    __syncthreads();

    const int base = chunk * HROWS;
    if (c < 32) {
        const float* zc = zT + (size_t)c * N_ROWS;
        for (int i = 0; i < HROWS / 256; ++i) {
            int r = base + t + 256 * i;
            int b = bidx[r];
            atomicAdd(&h[b], zc[r]);
        }
    } else {
        for (int i = 0; i < HROWS / 256; ++i) {
            int r = base + t + 256 * i;
            int b = bidx[r];
            atomicAdd(&h[b], 1.0f);
        }
    }
    __syncthreads();
    float* dst = hpart + (size_t)(chunk * 33 + c) * NB;
    #pragma unroll
    for (int i = 0; i < NB / 256; ++i) dst[t + 256 * i] = h[t + 256 * i];
}

// Deterministic reduction of partials -> counts, sum_z[b*32+c]
__global__ __launch_bounds__(1024) void vq_reduce(
    const float* __restrict__ hpart, float* __restrict__ counts,
    float* __restrict__ sum_z)
{
    const int c = blockIdx.x;     // 0..32
    const int b = threadIdx.x;    // 0..1023
    float acc = 0.0f;
    for (int chunk = 0; chunk < HCHUNKS; ++chunk)
        acc += hpart[(size_t)(chunk * 33 + c) * NB + b];
    if (c < 32) sum_z[(size_t)b * DZ + c] = acc;
    else        counts[b] = acc;
}

__global__ __launch_bounds__(1024) void vq_finalize(
    const float* __restrict__ vectors, const float* __restrict__ assignments,
    const float* __restrict__ noise, const float* __restrict__ counts,
    const float* __restrict__ sum_z, const float* __restrict__ recon_acc,
    const float* __restrict__ commit_acc, float* __restrict__ out)
{
    __shared__ float a[NB];
    __shared__ unsigned char na[NB];
    __shared__ float rv[NB];
    __shared__ int ri[NB];
    __shared__ int s_max_idx;
    const int t = threadIdx.x;

    const float cnt = counts[t];
    const float ba = cnt / NBF;                 // batch_assign; ba*N == cnt exactly
    const float ae = 0.99f * assignments[t] + 0.01f * ba;
    a[t] = ae;
    na[t] = (ae * NBF < MIN_ASSIGN) ? 1 : 0;
    rv[t] = ba; ri[t] = t;
    __syncthreads();

    for (int s = NB / 2; s > 0; s >>= 1) {
        if (t < s) {
            float ov = rv[t + s]; int oi = ri[t + s];
            if (ov > rv[t] || (ov == rv[t] && oi < ri[t])) { rv[t] = ov; ri[t] = oi; }
        }
        __syncthreads();
    }
    if (t == 0) s_max_idx = ri[0];
    __syncthreads();
    const int mx = s_max_idx;

    if (t == 0) {
        for (int i = NB - 1; i >= 0; --i) {
            if (na[i]) {
                float v = 0.5f * a[mx];
                a[i] = v;
                a[mx] = v;
            }
        }
    }
    __syncthreads();

    out[1 + NB * DZ + t] = a[t];

    const bool dead = (na[t] != 0);
    #pragma unroll
    for (int c = 0; c < DZ; ++c) {
        float v2 = dead ? (vectors[mx * DZ + c] + noise[t * DZ + c])
                        : vectors[t * DZ + c];
        float mean = (cnt == 0.0f) ? v2 : (sum_z[(size_t)t * DZ + c] / cnt);
        out[1 + t * DZ + c] = 0.99f * v2 + 0.01f * mean;
    }

    if (t == 0) {
        float recon = 0.5f * (recon_acc[0] / NBF) + 32.0f * 1.8378770664093453f;
        float commit = commit_acc[0] / (NBF * (float)DZ);
        out[0] = recon + 0.25f * commit;
    }
}

// ---------- fallback (round-1) main kernel, used only if ws is too small ----------
__global__ __launch_bounds__(256) void vq_main_atomic(
    const float* __restrict__ x, const float* __restrict__ W_enc,
    const float* __restrict__ b_enc, const float* __restrict__ vectors,
    const float* __restrict__ vnorm, const float* __restrict__ mu_table,
    float* __restrict__ counts, float* __restrict__ sum_z,
    float* __restrict__ recon_acc, float* __restrict__ commit_acc)
{
    const int r = blockIdx.x * 256 + threadIdx.x;
    float xr[DX];
    const float4* xp = reinterpret_cast<const float4*>(x + (size_t)r * DX);
    #pragma unroll
    for (int i = 0; i < DX / 4; ++i) {
        float4 v = xp[i];
        xr[4 * i + 0] = v.x; xr[4 * i + 1] = v.y;
        xr[4 * i + 2] = v.z; xr[4 * i + 3] = v.w;
    }
    float z[DZ];
    #pragma unroll
    for (int c = 0; c < DZ; ++c) z[c] = b_enc[c];
    #pragma unroll
    for (int k = 0; k < DX; ++k) {
        float xk = xr[k];
        #pragma unroll
        for (int c = 0; c < DZ; ++c) z[c] = fmaf(xk, W_enc[k * DZ + c], z[c]);
    }
    float znorm = 0.0f;
    #pragma unroll
    for (int c = 0; c < DZ; ++c) znorm = fmaf(z[c], z[c], znorm);
    float zm2[DZ];
    #pragma unroll
    for (int c = 0; c < DZ; ++c) zm2[c] = -2.0f * z[c];

    float best = 3.4e38f;
    int bidx = 0;
    for (int j = 0; j < NB; ++j) {
        const float* vj = vectors + j * DZ;
        float s0 = vnorm[j], s1 = 0.0f, s2 = 0.0f, s3 = 0.0f;
        #pragma unroll
        for (int c = 0; c < DZ; c += 4) {
            s0 = fmaf(zm2[c + 0], vj[c + 0], s0);
            s1 = fmaf(zm2[c + 1], vj[c + 1], s1);
            s2 = fmaf(zm2[c + 2], vj[c + 2], s2);
            s3 = fmaf(zm2[c + 3], vj[c + 3], s3);
        }
        float s = (s0 + s1) + (s2 + s3);
        if (s < best) { best = s; bidx = j; }
    }
    float commit_row = znorm + best;

    float rs = 0.0f;
    const float4* mup = reinterpret_cast<const float4*>(mu_table + (size_t)bidx * DX);
    #pragma unroll
    for (int i = 0; i < DX / 4; ++i) {
        float4 m = mup[i];
        float d0 = xr[4 * i + 0] - m.x; rs = fmaf(d0, d0, rs);
        float d1 = xr[4 * i + 1] - m.y; rs = fmaf(d1, d1, rs);
        float d2 = xr[4 * i + 2] - m.z; rs = fmaf(d2, d2, rs);
        float d3 = xr[4 * i + 3] - m.w; rs = fmaf(d3, d3, rs);
    }
    atomicAdd(&counts[bidx], 1.0f);
    #pragma unroll
    for (int c = 0; c < DZ; ++c)
        atomicAdd(&sum_z[(size_t)bidx * DZ + c], -0.5f * zm2[c]);
    #pragma unroll
    for (int off = 32; off > 0; off >>= 1) {
        rs += __shfl_down(rs, off, 64);
        commit_row += __shfl_down(commit_row, off, 64);
    }
    if ((threadIdx.x & 63) == 0) {
        atomicAdd(recon_acc, rs);
        atomicAdd(commit_acc, commit_row);
    }
}

extern "C" void kernel_launch(void* const* d_in, const int* in_sizes, int n_in,
                              void* d_out, int out_size, void* d_ws, size_t ws_size,
                              hipStream_t stream)
{
    const float* x           = (const float*)d_in[0];
    const float* W_enc       = (const float*)d_in[1];
    const float* b_enc       = (const float*)d_in[2];
    const float* vectors     = (const float*)d_in[3];
    const float* W_dec       = (const float*)d_in[4];
    const float* b_dec       = (const float*)d_in[5];
    const float* assignments = (const float*)d_in[6];
    const float* noise       = (const float*)d_in[7];
    float* out = (float*)d_out;
    float* ws  = (float*)d_ws;

    if (ws_size >= (size_t)WS_TOTAL * sizeof(float)) {
        // ---- fast path: no global atomics in the hot loop ----
        zero_kernel<<<1, 256, 0, stream>>>(ws, 2);   // recon/commit accumulators
        vq_prep<<<NB, 64, 0, stream>>>(vectors, W_dec, b_dec,
                                       ws + WS_VNORM, ws + WS_MUTAB);
        vq_enc<<<N_ROWS / 256, 256, 0, stream>>>(x, W_enc, b_enc, ws + WS_ZT);
        vq_argmin<<<N_ROWS / 256, 256, 0, stream>>>(ws + WS_ZT, vectors,
            ws + WS_VNORM, ws + WS_MUTAB, x, (int*)(ws + WS_BIDX),
            ws + WS_RECON, ws + WS_COMMIT);
        vq_hist<<<33 * HCHUNKS, 256, 0, stream>>>(ws + WS_ZT,
            (const int*)(ws + WS_BIDX), ws + WS_HPART);
        vq_reduce<<<33, 1024, 0, stream>>>(ws + WS_HPART,
            ws + WS_COUNTS, ws + WS_SUMZ);
        vq_finalize<<<1, NB, 0, stream>>>(vectors, assignments, noise,
            ws + WS_COUNTS, ws + WS_SUMZ, ws + WS_RECON, ws + WS_COMMIT, out);
    } else {
        // ---- fallback: round-1 correct path ----
        zero_kernel<<<(FB_ZERO_N + 255) / 256, 256, 0, stream>>>(ws, FB_ZERO_N);
        vq_prep<<<NB, 64, 0, stream>>>(vectors, W_dec, b_dec,
                                       ws + FB_VNORM, ws + FB_MUTAB);
        vq_main_atomic<<<N_ROWS / 256, 256, 0, stream>>>(x, W_enc, b_enc, vectors,
            ws + FB_VNORM, ws + FB_MUTAB, ws + FB_COUNTS, ws + FB_SUMZ,
            ws + FB_RECON, ws + FB_COMMIT);
        vq_finalize<<<1, NB, 0, stream>>>(vectors, assignments, noise,
            ws + FB_COUNTS, ws + FB_SUMZ, ws + FB_RECON, ws + FB_COMMIT, out);
    }
}

// Round 3
// 498.687 us; speedup vs baseline: 3.6019x; 1.3676x over previous
//
#include <hip/hip_runtime.h>
#include <math.h>

// Problem constants (from reference setup_inputs)
#define N_ROWS 262144
#define DX 64
#define DZ 32
#define NB 1024
#define NBF 262144.0f
#define MIN_ASSIGN (0.1f / 1024.0f)

typedef short shortx8 __attribute__((ext_vector_type(8)));
typedef float floatx4 __attribute__((ext_vector_type(4)));

// ---------- fast-path workspace layout (float offsets) ----------
#define WS_RECON   0
#define WS_COMMIT  1
#define WS_VNORM   64
#define WS_MUTAB   1088                    // + 1024*64 = 65536
#define WS_VBF     66624                   // + 1024*32 bf16 = 16384 floats
#define WS_ZT      83008                   // + 32*262144 = 8388608 (z transposed [c][r])
#define WS_BIDX    8471616                 // + 262144 u16 = 131072 floats
#define WS_HPART   8602688                 // + 32*33*1024 = 1081344
#define WS_COUNTS  9684032                 // + 1024
#define WS_SUMZ    9685056                 // + 32768
#define WS_TOTAL   9717824                 // floats (~38.9 MB)
#define HCHUNKS 32
#define HROWS  (N_ROWS / HCHUNKS)          // 8192 rows per chunk

// ---------- fallback (round-1) workspace layout ----------
#define FB_RECON  0
#define FB_COMMIT 1
#define FB_COUNTS 64
#define FB_SUMZ   1088
#define FB_VNORM  33856
#define FB_MUTAB  34880
#define FB_ZERO_N 33856

static __device__ __forceinline__ short f2bf(float f) {
    union { float f; unsigned u; } v; v.f = f;
    unsigned r = v.u + 0x7FFFu + ((v.u >> 16) & 1u);   // RNE
    return (short)(r >> 16);
}

__global__ __launch_bounds__(256) void zero_kernel(float* __restrict__ p, int n) {
    int i = blockIdx.x * 256 + threadIdx.x;
    if (i < n) p[i] = 0.0f;
}

// Per-bin: vnorm, mu_table, bf16 codebook copy
__global__ __launch_bounds__(64) void vq_prep(
    const float* __restrict__ vectors, const float* __restrict__ W_dec,
    const float* __restrict__ b_dec, float* __restrict__ vnorm,
    float* __restrict__ mu_table, short* __restrict__ vbf)
{
    const int j = blockIdx.x;
    const int t = threadIdx.x;
    __shared__ float v[DZ];
    if (t < DZ) {
        float vv = vectors[j * DZ + t];
        v[t] = vv;
        vbf[j * DZ + t] = f2bf(vv);
    }
    __syncthreads();
    float m = b_dec[t];
    #pragma unroll
    for (int k = 0; k < DZ; ++k) m = fmaf(v[k], W_dec[k * DX + t], m);
    mu_table[(size_t)j * DX + t] = m;
    if (t == 0) {
        float s = 0.0f;
        #pragma unroll
        for (int k = 0; k < DZ; ++k) s = fmaf(v[k], v[k], s);
        vnorm[j] = s;
    }
}

// ---------- fused encoder + MFMA argmin ----------
// Block = 256 rows (4 waves x 64 rows). Phase 1: fp32 encoder -> zT (exact) +
// bf16(-2z) staged in LDS. Phase 2: codebook streamed in 256-code chunks to
// LDS; per wave 4 row-tiles x 16 code-tiles x mfma_f32_16x16x32_bf16 with
// C initialized to vnorm[col]; per-lane running (min, argmin); shfl-xor reduce.
__global__ __launch_bounds__(256) void vq_encmin(
    const float* __restrict__ x, const float* __restrict__ W_enc,
    const float* __restrict__ b_enc, const short* __restrict__ vbf,
    const float* __restrict__ vnorm, float* __restrict__ zT,
    unsigned short* __restrict__ bidx_out)
{
    __shared__ __attribute__((aligned(16))) short zbf[256 * 40];   // 80 B rows (pad vs conflicts)
    __shared__ __attribute__((aligned(16))) short vchunk[256 * 40];
    __shared__ float vnl[NB];
    const int t = threadIdx.x;
    const int r = blockIdx.x * 256 + t;

    for (int i = t; i < NB; i += 256) vnl[i] = vnorm[i];

    // ---- phase 1: fp32 encoder (bit-identical op order to round 1) ----
    {
        float xr[DX];
        const float4* xp = reinterpret_cast<const float4*>(x + (size_t)r * DX);
        #pragma unroll
        for (int i = 0; i < DX / 4; ++i) {
            float4 v = xp[i];
            xr[4 * i + 0] = v.x; xr[4 * i + 1] = v.y;
            xr[4 * i + 2] = v.z; xr[4 * i + 3] = v.w;
        }
        float z[DZ];
        #pragma unroll
        for (int c = 0; c < DZ; ++c) z[c] = b_enc[c];
        #pragma unroll
        for (int k = 0; k < DX; ++k) {
            float xk = xr[k];
            #pragma unroll
            for (int c = 0; c < DZ; ++c) z[c] = fmaf(xk, W_enc[k * DZ + c], z[c]);
        }
        #pragma unroll
        for (int c = 0; c < DZ; ++c) zT[(size_t)c * N_ROWS + r] = z[c];
        #pragma unroll
        for (int c = 0; c < DZ; c += 2) {
            unsigned lo = (unsigned short)f2bf(-2.0f * z[c]);
            unsigned hi = (unsigned short)f2bf(-2.0f * z[c + 1]);
            *(unsigned*)&zbf[t * 40 + c] = lo | (hi << 16);
        }
    }
    __syncthreads();

    // ---- phase 2: MFMA argmin ----
    const int w  = t >> 6;          // wave id: rows w*64 .. w*64+63
    const int l  = t & 63;
    const int lm = l & 15;          // col-within-tile / row-within-tile (A)
    const int lq = l >> 4;          // quad

    shortx8 afrag[4];
    #pragma unroll
    for (int rt = 0; rt < 4; ++rt)
        afrag[rt] = *(const shortx8*)&zbf[(w * 64 + rt * 16 + lm) * 40 + lq * 8];

    float best[16];
    int   bj[16];
    #pragma unroll
    for (int k = 0; k < 16; ++k) { best[k] = 3.4e38f; bj[k] = 0; }

    for (int chunk = 0; chunk < 4; ++chunk) {
        __syncthreads();
        // cooperative load: 256 codes x 32 bf16 -> LDS (padded 40-short rows)
        const shortx8* src = (const shortx8*)(vbf + chunk * 256 * DZ);
        #pragma unroll
        for (int i = 0; i < 4; ++i) {
            int u = i * 256 + t;
            int code = u >> 2, part = u & 3;
            *(shortx8*)&vchunk[code * 40 + part * 8] = src[u];
        }
        __syncthreads();

        #pragma unroll 4
        for (int jt = 0; jt < 16; ++jt) {
            shortx8 bfrag = *(const shortx8*)&vchunk[(jt * 16 + lm) * 40 + lq * 8];
            int jbase = chunk * 256 + jt * 16 + lm;     // this lane's code index
            float vn = vnl[jbase];
            floatx4 cin = {vn, vn, vn, vn};
            #pragma unroll
            for (int rt = 0; rt < 4; ++rt) {
                floatx4 acc = __builtin_amdgcn_mfma_f32_16x16x32_bf16(
                    afrag[rt], bfrag, cin, 0, 0, 0);
                #pragma unroll
                for (int reg = 0; reg < 4; ++reg) {
                    float s = acc[reg];
                    int k = rt * 4 + reg;
                    bool lt = s < best[k];
                    best[k] = lt ? s : best[k];
                    bj[k]   = lt ? jbase : bj[k];
                }
            }
        }
    }

    // cross-lane reduce over the 16 columns (lanes sharing lq); ties -> lower j
    #pragma unroll
    for (int k = 0; k < 16; ++k) {
        float b = best[k]; int j = bj[k];
        #pragma unroll
        for (int m = 1; m <= 8; m <<= 1) {
            float ob = __shfl_xor(b, m, 64);
            int   oj = __shfl_xor(j, m, 64);
            if (ob < b || (ob == b && oj < j)) { b = ob; j = oj; }
        }
        if (lm == 0) {
            int rt = k >> 2, reg = k & 3;
            int row = blockIdx.x * 256 + w * 64 + rt * 16 + lq * 4 + reg;
            bidx_out[row] = (unsigned short)j;
        }
    }
}

// Exact fp32 recon + commit from chosen index (outputs stay fp32-grade)
__global__ __launch_bounds__(256) void vq_epilogue(
    const float* __restrict__ x, const float* __restrict__ zT,
    const float* __restrict__ vectors, const float* __restrict__ mu_table,
    const unsigned short* __restrict__ bidx,
    float* __restrict__ recon_acc, float* __restrict__ commit_acc)
{
    const int r = blockIdx.x * 256 + threadIdx.x;
    const int b = bidx[r];

    float rs = 0.0f;
    const float4* xp = reinterpret_cast<const float4*>(x + (size_t)r * DX);
    const float4* mp = reinterpret_cast<const float4*>(mu_table + (size_t)b * DX);
    #pragma unroll
    for (int i = 0; i < DX / 4; ++i) {
        float4 xv = xp[i];
        float4 m  = mp[i];
        float d0 = xv.x - m.x; rs = fmaf(d0, d0, rs);
        float d1 = xv.y - m.y; rs = fmaf(d1, d1, rs);
        float d2 = xv.z - m.z; rs = fmaf(d2, d2, rs);
        float d3 = xv.w - m.w; rs = fmaf(d3, d3, rs);
    }

    float cs = 0.0f;
    const float4* vp = reinterpret_cast<const float4*>(vectors + (size_t)b * DZ);
    #pragma unroll
    for (int i = 0; i < DZ / 4; ++i) {
        float4 v = vp[i];
        float d0 = zT[(size_t)(4 * i + 0) * N_ROWS + r] - v.x; cs = fmaf(d0, d0, cs);
        float d1 = zT[(size_t)(4 * i + 1) * N_ROWS + r] - v.y; cs = fmaf(d1, d1, cs);
        float d2 = zT[(size_t)(4 * i + 2) * N_ROWS + r] - v.z; cs = fmaf(d2, d2, cs);
        float d3 = zT[(size_t)(4 * i + 3) * N_ROWS + r] - v.w; cs = fmaf(d3, d3, cs);
    }

    #pragma unroll
    for (int off = 32; off > 0; off >>= 1) {
        rs += __shfl_down(rs, off, 64);
        cs += __shfl_down(cs, off, 64);
    }
    if ((threadIdx.x & 63) == 0) {
        atomicAdd(recon_acc, rs);
        atomicAdd(commit_acc, cs);
    }
}

// Component-sliced LDS histogram (LDS atomics only)
__global__ __launch_bounds__(256) void vq_hist(
    const float* __restrict__ zT, const unsigned short* __restrict__ bidx,
    float* __restrict__ hpart)
{
    const int c     = blockIdx.x % 33;
    const int chunk = blockIdx.x / 33;
    const int t = threadIdx.x;
    __shared__ float h[NB];
    #pragma unroll
    for (int i = 0; i < NB / 256; ++i) h[t + 256 * i] = 0.0f;
    __syncthreads();

    const int base = chunk * HROWS;
    if (c < 32) {
        const float* zc = zT + (size_t)c * N_ROWS;
        for (int i = 0; i < HROWS / 256; ++i) {
            int r = base + t + 256 * i;
            atomicAdd(&h[bidx[r]], zc[r]);
        }
    } else {
        for (int i = 0; i < HROWS / 256; ++i) {
            int r = base + t + 256 * i;
            atomicAdd(&h[bidx[r]], 1.0f);
        }
    }
    __syncthreads();
    float* dst = hpart + (size_t)(chunk * 33 + c) * NB;
    #pragma unroll
    for (int i = 0; i < NB / 256; ++i) dst[t + 256 * i] = h[t + 256 * i];
}

__global__ __launch_bounds__(1024) void vq_reduce(
    const float* __restrict__ hpart, float* __restrict__ counts,
    float* __restrict__ sum_z)
{
    const int c = blockIdx.x;     // 0..32
    const int b = threadIdx.x;    // 0..1023
    float acc = 0.0f;
    for (int chunk = 0; chunk < HCHUNKS; ++chunk)
        acc += hpart[(size_t)(chunk * 33 + c) * NB + b];
    if (c < 32) sum_z[(size_t)b * DZ + c] = acc;
    else        counts[b] = acc;
}

__global__ __launch_bounds__(1024) void vq_finalize(
    const float* __restrict__ vectors, const float* __restrict__ assignments,
    const float* __restrict__ noise, const float* __restrict__ counts,
    const float* __restrict__ sum_z, const float* __restrict__ recon_acc,
    const float* __restrict__ commit_acc, float* __restrict__ out)
{
    __shared__ float a[NB];
    __shared__ unsigned char na[NB];
    __shared__ float rv[NB];
    __shared__ int ri[NB];
    __shared__ int s_max_idx;
    const int t = threadIdx.x;

    const float cnt = counts[t];
    const float ba = cnt / NBF;
    const float ae = 0.99f * assignments[t] + 0.01f * ba;
    a[t] = ae;
    na[t] = (ae * NBF < MIN_ASSIGN) ? 1 : 0;
    rv[t] = ba; ri[t] = t;
    __syncthreads();

    for (int s = NB / 2; s > 0; s >>= 1) {
        if (t < s) {
            float ov = rv[t + s]; int oi = ri[t + s];
            if (ov > rv[t] || (ov == rv[t] && oi < ri[t])) { rv[t] = ov; ri[t] = oi; }
        }
        __syncthreads();
    }
    if (t == 0) s_max_idx = ri[0];
    __syncthreads();
    const int mx = s_max_idx;

    if (t == 0) {
        for (int i = NB - 1; i >= 0; --i) {
            if (na[i]) {
                float v = 0.5f * a[mx];
                a[i] = v;
                a[mx] = v;
            }
        }
    }
    __syncthreads();

    out[1 + NB * DZ + t] = a[t];

    const bool dead = (na[t] != 0);
    #pragma unroll
    for (int c = 0; c < DZ; ++c) {
        float v2 = dead ? (vectors[mx * DZ + c] + noise[t * DZ + c])
                        : vectors[t * DZ + c];
        float mean = (cnt == 0.0f) ? v2 : (sum_z[(size_t)t * DZ + c] / cnt);
        out[1 + t * DZ + c] = 0.99f * v2 + 0.01f * mean;
    }

    if (t == 0) {
        float recon = 0.5f * (recon_acc[0] / NBF) + 32.0f * 1.8378770664093453f;
        float commit = commit_acc[0] / (NBF * (float)DZ);
        out[0] = recon + 0.25f * commit;
    }
}

// ---------- fallback (round-1) main kernel, used only if ws is too small ----------
__global__ __launch_bounds__(256) void vq_main_atomic(
    const float* __restrict__ x, const float* __restrict__ W_enc,
    const float* __restrict__ b_enc, const float* __restrict__ vectors,
    const float* __restrict__ vnorm, const float* __restrict__ mu_table,
    float* __restrict__ counts, float* __restrict__ sum_z,
    float* __restrict__ recon_acc, float* __restrict__ commit_acc)
{
    const int r = blockIdx.x * 256 + threadIdx.x;
    float xr[DX];
    const float4* xp = reinterpret_cast<const float4*>(x + (size_t)r * DX);
    #pragma unroll
    for (int i = 0; i < DX / 4; ++i) {
        float4 v = xp[i];
        xr[4 * i + 0] = v.x; xr[4 * i + 1] = v.y;
        xr[4 * i + 2] = v.z; xr[4 * i + 3] = v.w;
    }
    float z[DZ];
    #pragma unroll
    for (int c = 0; c < DZ; ++c) z[c] = b_enc[c];
    #pragma unroll
    for (int k = 0; k < DX; ++k) {
        float xk = xr[k];
        #pragma unroll
        for (int c = 0; c < DZ; ++c) z[c] = fmaf(xk, W_enc[k * DZ + c], z[c]);
    }
    float znorm = 0.0f;
    #pragma unroll
    for (int c = 0; c < DZ; ++c) znorm = fmaf(z[c], z[c], znorm);
    float zm2[DZ];
    #pragma unroll
    for (int c = 0; c < DZ; ++c) zm2[c] = -2.0f * z[c];

    float best = 3.4e38f;
    int bidx = 0;
    for (int j = 0; j < NB; ++j) {
        const float* vj = vectors + j * DZ;
        float s0 = vnorm[j], s1 = 0.0f, s2 = 0.0f, s3 = 0.0f;
        #pragma unroll
        for (int c = 0; c < DZ; c += 4) {
            s0 = fmaf(zm2[c + 0], vj[c + 0], s0);
            s1 = fmaf(zm2[c + 1], vj[c + 1], s1);
            s2 = fmaf(zm2[c + 2], vj[c + 2], s2);
            s3 = fmaf(zm2[c + 3], vj[c + 3], s3);
        }
        float s = (s0 + s1) + (s2 + s3);
        if (s < best) { best = s; bidx = j; }
    }
    float commit_row = znorm + best;

    float rs = 0.0f;
    const float4* mup = reinterpret_cast<const float4*>(mu_table + (size_t)bidx * DX);
    #pragma unroll
    for (int i = 0; i < DX / 4; ++i) {
        float4 m = mup[i];
        float d0 = xr[4 * i + 0] - m.x; rs = fmaf(d0, d0, rs);
        float d1 = xr[4 * i + 1] - m.y; rs = fmaf(d1, d1, rs);
        float d2 = xr[4 * i + 2] - m.z; rs = fmaf(d2, d2, rs);
        float d3 = xr[4 * i + 3] - m.w; rs = fmaf(d3, d3, rs);
    }
    atomicAdd(&counts[bidx], 1.0f);
    #pragma unroll
    for (int c = 0; c < DZ; ++c)
        atomicAdd(&sum_z[(size_t)bidx * DZ + c], -0.5f * zm2[c]);
    #pragma unroll
    for (int off = 32; off > 0; off >>= 1) {
        rs += __shfl_down(rs, off, 64);
        commit_row += __shfl_down(commit_row, off, 64);
    }
    if ((threadIdx.x & 63) == 0) {
        atomicAdd(recon_acc, rs);
        atomicAdd(commit_acc, commit_row);
    }
}

extern "C" void kernel_launch(void* const* d_in, const int* in_sizes, int n_in,
                              void* d_out, int out_size, void* d_ws, size_t ws_size,
                              hipStream_t stream)
{
    const float* x           = (const float*)d_in[0];
    const float* W_enc       = (const float*)d_in[1];
    const float* b_enc       = (const float*)d_in[2];
    const float* vectors     = (const float*)d_in[3];
    const float* W_dec       = (const float*)d_in[4];
    const float* b_dec       = (const float*)d_in[5];
    const float* assignments = (const float*)d_in[6];
    const float* noise       = (const float*)d_in[7];
    float* out = (float*)d_out;
    float* ws  = (float*)d_ws;

    if (ws_size >= (size_t)WS_TOTAL * sizeof(float)) {
        zero_kernel<<<1, 256, 0, stream>>>(ws, 2);
        vq_prep<<<NB, 64, 0, stream>>>(vectors, W_dec, b_dec,
            ws + WS_VNORM, ws + WS_MUTAB, (short*)(ws + WS_VBF));
        vq_encmin<<<N_ROWS / 256, 256, 0, stream>>>(x, W_enc, b_enc,
            (const short*)(ws + WS_VBF), ws + WS_VNORM, ws + WS_ZT,
            (unsigned short*)(ws + WS_BIDX));
        vq_epilogue<<<N_ROWS / 256, 256, 0, stream>>>(x, ws + WS_ZT, vectors,
            ws + WS_MUTAB, (const unsigned short*)(ws + WS_BIDX),
            ws + WS_RECON, ws + WS_COMMIT);
        vq_hist<<<33 * HCHUNKS, 256, 0, stream>>>(ws + WS_ZT,
            (const unsigned short*)(ws + WS_BIDX), ws + WS_HPART);
        vq_reduce<<<33, 1024, 0, stream>>>(ws + WS_HPART,
            ws + WS_COUNTS, ws + WS_SUMZ);
        vq_finalize<<<1, NB, 0, stream>>>(vectors, assignments, noise,
            ws + WS_COUNTS, ws + WS_SUMZ, ws + WS_RECON, ws + WS_COMMIT, out);
    } else {
        zero_kernel<<<(FB_ZERO_N + 255) / 256, 256, 0, stream>>>(ws, FB_ZERO_N);
        vq_prep<<<NB, 64, 0, stream>>>(vectors, W_dec, b_dec,
            ws + FB_VNORM, ws + FB_MUTAB, (short*)(ws + FB_MUTAB + NB * DX));
        vq_main_atomic<<<N_ROWS / 256, 256, 0, stream>>>(x, W_enc, b_enc, vectors,
            ws + FB_VNORM, ws + FB_MUTAB, ws + FB_COUNTS, ws + FB_SUMZ,
            ws + FB_RECON, ws + FB_COMMIT);
        vq_finalize<<<1, NB, 0, stream>>>(vectors, assignments, noise,
            ws + FB_COUNTS, ws + FB_SUMZ, ws + FB_RECON, ws + FB_COMMIT, out);
    }
}

// Round 4
// 486.955 us; speedup vs baseline: 3.6886x; 1.0241x over previous
//
#include <hip/hip_runtime.h>
#include <math.h>

// Problem constants (from reference setup_inputs)
#define N_ROWS 262144
#define DX 64
#define DZ 32
#define NB 1024
#define NBF 262144.0f
#define MIN_ASSIGN (0.1f / 1024.0f)

typedef short shortx8 __attribute__((ext_vector_type(8)));
typedef float floatx4 __attribute__((ext_vector_type(4)));

// ---------- fast-path workspace layout (float offsets) ----------
#define WS_RECON   0
#define WS_COMMIT  1
#define WS_VNORM   64                      // + 1024
#define WS_MUTAB   1088                    // + 1024*64 = 65536
#define WS_VBF     66624                   // 1024*32 bf16 = 16384 floats
#define WS_ZBT     83008                   // 32*262144 bf16 (z transposed) = 4194304 floats
#define WS_BIDX    4277312                 // 262144 u16 = 131072 floats
#define WS_HPART   4408384                 // 32*33*1024 = 1081344
#define WS_COUNTS  5489728                 // + 1024
#define WS_SUMZ    5490752                 // + 32768
#define WS_TOTAL   5523520                 // floats (~22.1 MB)
#define HCHUNKS 32
#define HROWS  (N_ROWS / HCHUNKS)          // 8192 rows per chunk

// ---------- fallback (round-1) workspace layout ----------
#define FB_RECON  0
#define FB_COMMIT 1
#define FB_COUNTS 64
#define FB_SUMZ   1088
#define FB_VNORM  33856
#define FB_MUTAB  34880
#define FB_ZERO_N 33856

static __device__ __forceinline__ short f2bf(float f) {
    union { float f; unsigned u; } v; v.f = f;
    unsigned r = v.u + 0x7FFFu + ((v.u >> 16) & 1u);   // RNE
    return (short)(r >> 16);
}
static __device__ __forceinline__ float bf2f(unsigned short h) {
    union { unsigned u; float f; } v; v.u = ((unsigned)h) << 16;
    return v.f;
}

__global__ __launch_bounds__(256) void zero_kernel(float* __restrict__ p, int n) {
    int i = blockIdx.x * 256 + threadIdx.x;
    if (i < n) p[i] = 0.0f;
}

// Per-bin: vnorm, mu_table, bf16 codebook; block 0 zeroes the accumulators.
__global__ __launch_bounds__(64) void vq_prep(
    const float* __restrict__ vectors, const float* __restrict__ W_dec,
    const float* __restrict__ b_dec, float* __restrict__ vnorm,
    float* __restrict__ mu_table, short* __restrict__ vbf,
    float* __restrict__ accums)
{
    const int j = blockIdx.x;
    const int t = threadIdx.x;
    if (j == 0 && t < 2) accums[t] = 0.0f;
    __shared__ float v[DZ];
    if (t < DZ) {
        float vv = vectors[j * DZ + t];
        v[t] = vv;
        vbf[j * DZ + t] = f2bf(vv);
    }
    __syncthreads();
    float m = b_dec[t];
    #pragma unroll
    for (int k = 0; k < DZ; ++k) m = fmaf(v[k], W_dec[k * DX + t], m);
    mu_table[(size_t)j * DX + t] = m;
    if (t == 0) {
        float s = 0.0f;
        #pragma unroll
        for (int k = 0; k < DZ; ++k) s = fmaf(v[k], v[k], s);
        vnorm[j] = s;
    }
}

// ---------- fused encoder + MFMA argmin + epilogue ----------
// Block = 256 rows (4 waves x 64). Phase 1: fp32 encoder; z stored bf16
// transposed (for hist); bf16(-2z) staged in LDS for A-fragments.
// Phase 2: 64 code-tiles; B-fragment + vnorm read straight from global
// (64 KB codebook, L1/L2-resident); mfma_f32_16x16x32_bf16 with C=vnorm;
// per-lane running min; shfl-xor reduce; best/bidx -> LDS.
// Phase 3: per-thread exact recon ||x-mu[b]||^2 (x reloaded), commit =
// znorm + best(score); wave-reduce, one atomic pair per wave.
__global__ __launch_bounds__(256, 6) void vq_encmin(
    const float* __restrict__ x, const float* __restrict__ W_enc,
    const float* __restrict__ b_enc, const short* __restrict__ vbf,
    const float* __restrict__ vnorm, const float* __restrict__ mu_table,
    unsigned short* __restrict__ zbt, unsigned short* __restrict__ bidx_out,
    float* __restrict__ recon_acc, float* __restrict__ commit_acc)
{
    __shared__ __attribute__((aligned(16))) short zbf[256 * 40];  // 80B rows (conflict pad)
    __shared__ float sbest[256];
    __shared__ unsigned short sbidx[256];
    const int t = threadIdx.x;
    const int r = blockIdx.x * 256 + t;

    // ---- phase 1: fp32 encoder (bit-identical op order to round 1) ----
    float znorm;
    {
        float xr[DX];
        const float4* xp = reinterpret_cast<const float4*>(x + (size_t)r * DX);
        #pragma unroll
        for (int i = 0; i < DX / 4; ++i) {
            float4 v = xp[i];
            xr[4 * i + 0] = v.x; xr[4 * i + 1] = v.y;
            xr[4 * i + 2] = v.z; xr[4 * i + 3] = v.w;
        }
        float z[DZ];
        #pragma unroll
        for (int c = 0; c < DZ; ++c) z[c] = b_enc[c];
        #pragma unroll
        for (int k = 0; k < DX; ++k) {
            float xk = xr[k];
            #pragma unroll
            for (int c = 0; c < DZ; ++c) z[c] = fmaf(xk, W_enc[k * DZ + c], z[c]);
        }
        znorm = 0.0f;
        #pragma unroll
        for (int c = 0; c < DZ; ++c) znorm = fmaf(z[c], z[c], znorm);
        #pragma unroll
        for (int c = 0; c < DZ; ++c)
            zbt[(size_t)c * N_ROWS + r] = (unsigned short)f2bf(z[c]);
        #pragma unroll
        for (int c = 0; c < DZ; c += 2) {
            unsigned lo = (unsigned short)f2bf(-2.0f * z[c]);
            unsigned hi = (unsigned short)f2bf(-2.0f * z[c + 1]);
            *(unsigned*)&zbf[t * 40 + c] = lo | (hi << 16);
        }
    }
    __syncthreads();

    // ---- phase 2: MFMA argmin ----
    const int w  = t >> 6;          // wave id: rows w*64 .. w*64+63
    const int l  = t & 63;
    const int lm = l & 15;
    const int lq = l >> 4;

    shortx8 afrag[4];
    #pragma unroll
    for (int rt = 0; rt < 4; ++rt)
        afrag[rt] = *(const shortx8*)&zbf[(w * 64 + rt * 16 + lm) * 40 + lq * 8];

    float best[16];
    int   bj[16];
    #pragma unroll
    for (int k = 0; k < 16; ++k) { best[k] = 3.4e38f; bj[k] = 0; }

    #pragma unroll 4
    for (int jt = 0; jt < 64; ++jt) {
        const int jbase = jt * 16 + lm;     // this lane's code index
        shortx8 bfrag = *(const shortx8*)(vbf + jbase * DZ + lq * 8);
        float vn = vnorm[jbase];
        floatx4 cin = {vn, vn, vn, vn};
        #pragma unroll
        for (int rt = 0; rt < 4; ++rt) {
            floatx4 acc = __builtin_amdgcn_mfma_f32_16x16x32_bf16(
                afrag[rt], bfrag, cin, 0, 0, 0);
            #pragma unroll
            for (int reg = 0; reg < 4; ++reg) {
                float s = acc[reg];
                int k = rt * 4 + reg;
                bool lt = s < best[k];
                best[k] = lt ? s : best[k];
                bj[k]   = lt ? jbase : bj[k];
            }
        }
    }

    // cross-lane reduce over the 16 columns; ties -> lower j
    #pragma unroll
    for (int k = 0; k < 16; ++k) {
        float b = best[k]; int j = bj[k];
        #pragma unroll
        for (int m = 1; m <= 8; m <<= 1) {
            float ob = __shfl_xor(b, m, 64);
            int   oj = __shfl_xor(j, m, 64);
            if (ob < b || (ob == b && oj < j)) { b = ob; j = oj; }
        }
        if (lm == 0) {
            int rt = k >> 2, reg = k & 3;
            int rl = w * 64 + rt * 16 + lq * 4 + reg;   // row within block
            sbest[rl] = b;
            sbidx[rl] = (unsigned short)j;
        }
    }
    __syncthreads();

    // ---- phase 3: epilogue (per-thread, own row) ----
    const int b = sbidx[t];
    float commit = znorm + sbest[t];        // == d2_min (bf16-score precision)
    bidx_out[r] = (unsigned short)b;

    float rs = 0.0f;
    const float4* xp = reinterpret_cast<const float4*>(x + (size_t)r * DX);
    const float4* mp = reinterpret_cast<const float4*>(mu_table + (size_t)b * DX);
    #pragma unroll
    for (int i = 0; i < DX / 4; ++i) {
        float4 xv = xp[i];
        float4 m  = mp[i];
        float d0 = xv.x - m.x; rs = fmaf(d0, d0, rs);
        float d1 = xv.y - m.y; rs = fmaf(d1, d1, rs);
        float d2 = xv.z - m.z; rs = fmaf(d2, d2, rs);
        float d3 = xv.w - m.w; rs = fmaf(d3, d3, rs);
    }

    #pragma unroll
    for (int off = 32; off > 0; off >>= 1) {
        rs     += __shfl_down(rs, off, 64);
        commit += __shfl_down(commit, off, 64);
    }
    if ((t & 63) == 0) {
        atomicAdd(recon_acc, rs);
        atomicAdd(commit_acc, commit);
    }
}

// Component-sliced LDS histogram over bf16 zT (LDS atomics only)
__global__ __launch_bounds__(256) void vq_hist(
    const unsigned short* __restrict__ zbt, const unsigned short* __restrict__ bidx,
    float* __restrict__ hpart)
{
    const int c     = blockIdx.x % 33;
    const int chunk = blockIdx.x / 33;
    const int t = threadIdx.x;
    __shared__ float h[NB];
    #pragma unroll
    for (int i = 0; i < NB / 256; ++i) h[t + 256 * i] = 0.0f;
    __syncthreads();

    const int base = chunk * HROWS;
    if (c < 32) {
        const unsigned short* zc = zbt + (size_t)c * N_ROWS;
        for (int i = 0; i < HROWS / 256; ++i) {
            int r = base + t + 256 * i;
            atomicAdd(&h[bidx[r]], bf2f(zc[r]));
        }
    } else {
        for (int i = 0; i < HROWS / 256; ++i) {
            int r = base + t + 256 * i;
            atomicAdd(&h[bidx[r]], 1.0f);
        }
    }
    __syncthreads();
    float* dst = hpart + (size_t)(chunk * 33 + c) * NB;
    #pragma unroll
    for (int i = 0; i < NB / 256; ++i) dst[t + 256 * i] = h[t + 256 * i];
}

__global__ __launch_bounds__(1024) void vq_reduce(
    const float* __restrict__ hpart, float* __restrict__ counts,
    float* __restrict__ sum_z)
{
    const int c = blockIdx.x;     // 0..32
    const int b = threadIdx.x;    // 0..1023
    float acc = 0.0f;
    for (int chunk = 0; chunk < HCHUNKS; ++chunk)
        acc += hpart[(size_t)(chunk * 33 + c) * NB + b];
    if (c < 32) sum_z[(size_t)b * DZ + c] = acc;
    else        counts[b] = acc;
}

__global__ __launch_bounds__(1024) void vq_finalize(
    const float* __restrict__ vectors, const float* __restrict__ assignments,
    const float* __restrict__ noise, const float* __restrict__ counts,
    const float* __restrict__ sum_z, const float* __restrict__ recon_acc,
    const float* __restrict__ commit_acc, float* __restrict__ out)
{
    __shared__ float a[NB];
    __shared__ int nad[NB];
    __shared__ int ssum[NB];
    __shared__ float rv[NB];
    __shared__ int ri[NB];
    __shared__ int s_max_idx;
    const int t = threadIdx.x;

    const float cnt = counts[t];
    const float ba = cnt / NBF;                 // batch_assign; ba*N == cnt exactly
    const float ae = 0.99f * assignments[t] + 0.01f * ba;
    a[t] = ae;
    const int dead = (ae * NBF < MIN_ASSIGN) ? 1 : 0;
    nad[t] = dead;
    ssum[t] = dead;
    rv[t] = ba; ri[t] = t;
    __syncthreads();

    // argmax(batch_assign), first occurrence on ties
    for (int s = NB / 2; s > 0; s >>= 1) {
        if (t < s) {
            float ov = rv[t + s]; int oi = ri[t + s];
            if (ov > rv[t] || (ov == rv[t] && oi < ri[t])) { rv[t] = ov; ri[t] = oi; }
        }
        __syncthreads();
    }
    if (t == 0) s_max_idx = ri[0];
    __syncthreads();
    const int mx = s_max_idx;
    const float a0mx = a[mx];                   // a[mx] before any scan update
    const int na_mx = nad[mx];

    // suffix sum: ssum[t] = # dead with index >= t  (processing rank of dead t)
    for (int off = 1; off < NB; off <<= 1) {
        int v = (t + off < NB) ? ssum[t + off] : 0;
        __syncthreads();
        ssum[t] += v;
        __syncthreads();
    }
    const int K = ssum[0];                      // total dead

    // closed form of the sequential scan (i = NB-1 .. 0):
    // dead i gets a0mx / 2^rank(i); a[mx] ends at a0mx / 2^K (if K>0)
    float av = a[t];
    if (dead) av = ldexpf(a0mx, -ssum[t]);
    if (t == mx && K > 0) av = ldexpf(a0mx, -K);
    out[1 + NB * DZ + t] = av;

    // vecs2 + new_vectors. If mx itself is dead, codes processed after it
    // (index < mx) see vectors[mx] + noise[mx].
    const float mxn = (dead && t < mx && na_mx) ? 1.0f : 0.0f;
    #pragma unroll
    for (int c = 0; c < DZ; ++c) {
        float v2 = vectors[t * DZ + c];
        if (dead) v2 = vectors[mx * DZ + c] + mxn * noise[mx * DZ + c] + noise[t * DZ + c];
        float mean = (cnt == 0.0f) ? v2 : (sum_z[(size_t)t * DZ + c] / cnt);
        out[1 + t * DZ + c] = 0.99f * v2 + 0.01f * mean;
    }

    if (t == 0) {
        float recon = 0.5f * (recon_acc[0] / NBF) + 32.0f * 1.8378770664093453f;
        float commit = commit_acc[0] / (NBF * (float)DZ);
        out[0] = recon + 0.25f * commit;
    }
}

// ---------- fallback (round-1) path, used only if ws is too small ----------
__global__ __launch_bounds__(64) void vq_prep_fb(
    const float* __restrict__ vectors, const float* __restrict__ W_dec,
    const float* __restrict__ b_dec, float* __restrict__ vnorm,
    float* __restrict__ mu_table)
{
    const int j = blockIdx.x;
    const int t = threadIdx.x;
    __shared__ float v[DZ];
    if (t < DZ) v[t] = vectors[j * DZ + t];
    __syncthreads();
    float m = b_dec[t];
    #pragma unroll
    for (int k = 0; k < DZ; ++k) m = fmaf(v[k], W_dec[k * DX + t], m);
    mu_table[(size_t)j * DX + t] = m;
    if (t == 0) {
        float s = 0.0f;
        #pragma unroll
        for (int k = 0; k < DZ; ++k) s = fmaf(v[k], v[k], s);
        vnorm[j] = s;
    }
}

__global__ __launch_bounds__(256) void vq_main_atomic(
    const float* __restrict__ x, const float* __restrict__ W_enc,
    const float* __restrict__ b_enc, const float* __restrict__ vectors,
    const float* __restrict__ vnorm, const float* __restrict__ mu_table,
    float* __restrict__ counts, float* __restrict__ sum_z,
    float* __restrict__ recon_acc, float* __restrict__ commit_acc)
{
    const int r = blockIdx.x * 256 + threadIdx.x;
    float xr[DX];
    const float4* xp = reinterpret_cast<const float4*>(x + (size_t)r * DX);
    #pragma unroll
    for (int i = 0; i < DX / 4; ++i) {
        float4 v = xp[i];
        xr[4 * i + 0] = v.x; xr[4 * i + 1] = v.y;
        xr[4 * i + 2] = v.z; xr[4 * i + 3] = v.w;
    }
    float z[DZ];
    #pragma unroll
    for (int c = 0; c < DZ; ++c) z[c] = b_enc[c];
    #pragma unroll
    for (int k = 0; k < DX; ++k) {
        float xk = xr[k];
        #pragma unroll
        for (int c = 0; c < DZ; ++c) z[c] = fmaf(xk, W_enc[k * DZ + c], z[c]);
    }
    float znorm = 0.0f;
    #pragma unroll
    for (int c = 0; c < DZ; ++c) znorm = fmaf(z[c], z[c], znorm);
    float zm2[DZ];
    #pragma unroll
    for (int c = 0; c < DZ; ++c) zm2[c] = -2.0f * z[c];

    float best = 3.4e38f;
    int bidx = 0;
    for (int j = 0; j < NB; ++j) {
        const float* vj = vectors + j * DZ;
        float s0 = vnorm[j], s1 = 0.0f, s2 = 0.0f, s3 = 0.0f;
        #pragma unroll
        for (int c = 0; c < DZ; c += 4) {
            s0 = fmaf(zm2[c + 0], vj[c + 0], s0);
            s1 = fmaf(zm2[c + 1], vj[c + 1], s1);
            s2 = fmaf(zm2[c + 2], vj[c + 2], s2);
            s3 = fmaf(zm2[c + 3], vj[c + 3], s3);
        }
        float s = (s0 + s1) + (s2 + s3);
        if (s < best) { best = s; bidx = j; }
    }
    float commit_row = znorm + best;

    float rs = 0.0f;
    const float4* mup = reinterpret_cast<const float4*>(mu_table + (size_t)bidx * DX);
    #pragma unroll
    for (int i = 0; i < DX / 4; ++i) {
        float4 m = mup[i];
        float d0 = xr[4 * i + 0] - m.x; rs = fmaf(d0, d0, rs);
        float d1 = xr[4 * i + 1] - m.y; rs = fmaf(d1, d1, rs);
        float d2 = xr[4 * i + 2] - m.z; rs = fmaf(d2, d2, rs);
        float d3 = xr[4 * i + 3] - m.w; rs = fmaf(d3, d3, rs);
    }
    atomicAdd(&counts[bidx], 1.0f);
    #pragma unroll
    for (int c = 0; c < DZ; ++c)
        atomicAdd(&sum_z[(size_t)bidx * DZ + c], -0.5f * zm2[c]);
    #pragma unroll
    for (int off = 32; off > 0; off >>= 1) {
        rs += __shfl_down(rs, off, 64);
        commit_row += __shfl_down(commit_row, off, 64);
    }
    if ((threadIdx.x & 63) == 0) {
        atomicAdd(recon_acc, rs);
        atomicAdd(commit_acc, commit_row);
    }
}

__global__ __launch_bounds__(1024) void vq_finalize_fb(
    const float* __restrict__ vectors, const float* __restrict__ assignments,
    const float* __restrict__ noise, const float* __restrict__ counts,
    const float* __restrict__ sum_z, const float* __restrict__ recon_acc,
    const float* __restrict__ commit_acc, float* __restrict__ out)
{
    __shared__ float a[NB];
    __shared__ unsigned char na[NB];
    __shared__ float rv[NB];
    __shared__ int ri[NB];
    __shared__ int s_max_idx;
    const int t = threadIdx.x;

    const float cnt = counts[t];
    const float ba = cnt / NBF;
    const float ae = 0.99f * assignments[t] + 0.01f * ba;
    a[t] = ae;
    na[t] = (ae * NBF < MIN_ASSIGN) ? 1 : 0;
    rv[t] = ba; ri[t] = t;
    __syncthreads();
    for (int s = NB / 2; s > 0; s >>= 1) {
        if (t < s) {
            float ov = rv[t + s]; int oi = ri[t + s];
            if (ov > rv[t] || (ov == rv[t] && oi < ri[t])) { rv[t] = ov; ri[t] = oi; }
        }
        __syncthreads();
    }
    if (t == 0) s_max_idx = ri[0];
    __syncthreads();
    const int mx = s_max_idx;
    if (t == 0) {
        for (int i = NB - 1; i >= 0; --i) {
            if (na[i]) { float v = 0.5f * a[mx]; a[i] = v; a[mx] = v; }
        }
    }
    __syncthreads();
    out[1 + NB * DZ + t] = a[t];
    const bool dead = (na[t] != 0);
    #pragma unroll
    for (int c = 0; c < DZ; ++c) {
        float v2 = dead ? (vectors[mx * DZ + c] + noise[t * DZ + c])
                        : vectors[t * DZ + c];
        float mean = (cnt == 0.0f) ? v2 : (sum_z[(size_t)t * DZ + c] / cnt);
        out[1 + t * DZ + c] = 0.99f * v2 + 0.01f * mean;
    }
    if (t == 0) {
        float recon = 0.5f * (recon_acc[0] / NBF) + 32.0f * 1.8378770664093453f;
        float commit = commit_acc[0] / (NBF * (float)DZ);
        out[0] = recon + 0.25f * commit;
    }
}

extern "C" void kernel_launch(void* const* d_in, const int* in_sizes, int n_in,
                              void* d_out, int out_size, void* d_ws, size_t ws_size,
                              hipStream_t stream)
{
    const float* x           = (const float*)d_in[0];
    const float* W_enc       = (const float*)d_in[1];
    const float* b_enc       = (const float*)d_in[2];
    const float* vectors     = (const float*)d_in[3];
    const float* W_dec       = (const float*)d_in[4];
    const float* b_dec       = (const float*)d_in[5];
    const float* assignments = (const float*)d_in[6];
    const float* noise       = (const float*)d_in[7];
    float* out = (float*)d_out;
    float* ws  = (float*)d_ws;

    if (ws_size >= (size_t)WS_TOTAL * sizeof(float)) {
        vq_prep<<<NB, 64, 0, stream>>>(vectors, W_dec, b_dec,
            ws + WS_VNORM, ws + WS_MUTAB, (short*)(ws + WS_VBF), ws + WS_RECON);
        vq_encmin<<<N_ROWS / 256, 256, 0, stream>>>(x, W_enc, b_enc,
            (const short*)(ws + WS_VBF), ws + WS_VNORM, ws + WS_MUTAB,
            (unsigned short*)(ws + WS_ZBT), (unsigned short*)(ws + WS_BIDX),
            ws + WS_RECON, ws + WS_COMMIT);
        vq_hist<<<33 * HCHUNKS, 256, 0, stream>>>(
            (const unsigned short*)(ws + WS_ZBT),
            (const unsigned short*)(ws + WS_BIDX), ws + WS_HPART);
        vq_reduce<<<33, 1024, 0, stream>>>(ws + WS_HPART,
            ws + WS_COUNTS, ws + WS_SUMZ);
        vq_finalize<<<1, NB, 0, stream>>>(vectors, assignments, noise,
            ws + WS_COUNTS, ws + WS_SUMZ, ws + WS_RECON, ws + WS_COMMIT, out);
    } else {
        zero_kernel<<<(FB_ZERO_N + 255) / 256, 256, 0, stream>>>(ws, FB_ZERO_N);
        vq_prep_fb<<<NB, 64, 0, stream>>>(vectors, W_dec, b_dec,
            ws + FB_VNORM, ws + FB_MUTAB);
        vq_main_atomic<<<N_ROWS / 256, 256, 0, stream>>>(x, W_enc, b_enc, vectors,
            ws + FB_VNORM, ws + FB_MUTAB, ws + FB_COUNTS, ws + FB_SUMZ,
            ws + FB_RECON, ws + FB_COMMIT);
        vq_finalize_fb<<<1, NB, 0, stream>>>(vectors, assignments, noise,
            ws + FB_COUNTS, ws + FB_SUMZ, ws + FB_RECON, ws + FB_COMMIT, out);
    }
}

// Round 5
// 400.115 us; speedup vs baseline: 4.4892x; 1.2170x over previous
//
#include <hip/hip_runtime.h>
#include <math.h>

// Problem constants (from reference setup_inputs)
#define N_ROWS 262144
#define DX 64
#define DZ 32
#define NB 1024
#define NBF 262144.0f
#define MIN_ASSIGN (0.1f / 1024.0f)
#define BIAS 512.0f

typedef short shortx8 __attribute__((ext_vector_type(8)));
typedef float floatx4 __attribute__((ext_vector_type(4)));

// ---------- fast-path workspace layout (float offsets) ----------
#define WS_RECON   0
#define WS_COMMIT  1
#define WS_VNORMB  64                      // + 1024   (vnorm + 512 bias)
#define WS_MUNORM  1088                    // + 1024   (||mu_j||^2)
#define WS_VBF     2112                    // 1024*32 bf16 = 16384 floats
#define WS_ZP      18496                   // 16 * 262144 u32 (bf16-pair z) = 4194304
#define WS_BIDX    4212800                 // 262144 u16 = 131072 floats
#define WS_HPART   4343872                 // 33*32*1024 = 1081344
#define WS_COUNTS  5425216                 // + 1024
#define WS_SUMZ    5426240                 // + 32768
#define WS_TOTAL   5459008                 // floats (~21.8 MB)
#define HCHUNKS 32
#define HROWS  (N_ROWS / HCHUNKS)          // 8192 rows per chunk

// ---------- fallback (round-1) workspace layout ----------
#define FB_RECON  0
#define FB_COMMIT 1
#define FB_COUNTS 64
#define FB_SUMZ   1088
#define FB_VNORM  33856
#define FB_MUTAB  34880
#define FB_ZERO_N 33856

static __device__ __forceinline__ short f2bf(float f) {
    union { float f; unsigned u; } v; v.f = f;
    unsigned r = v.u + 0x7FFFu + ((v.u >> 16) & 1u);   // RNE
    return (short)(r >> 16);
}

__global__ __launch_bounds__(256) void zero_kernel(float* __restrict__ p, int n) {
    int i = blockIdx.x * 256 + threadIdx.x;
    if (i < n) p[i] = 0.0f;
}

// Per-bin: biased vnorm, ||mu_j||^2, bf16 codebook; block 0 zeroes accumulators.
__global__ __launch_bounds__(64) void vq_prep(
    const float* __restrict__ vectors, const float* __restrict__ W_dec,
    const float* __restrict__ b_dec, float* __restrict__ vnormb,
    float* __restrict__ munormb, short* __restrict__ vbf,
    float* __restrict__ accums)
{
    const int j = blockIdx.x;
    const int t = threadIdx.x;
    if (j == 0 && t < 2) accums[t] = 0.0f;
    __shared__ float v[DZ];
    if (t < DZ) {
        float vv = vectors[j * DZ + t];
        v[t] = vv;
        vbf[j * DZ + t] = f2bf(vv);
    }
    __syncthreads();
    float m = b_dec[t];
    #pragma unroll
    for (int k = 0; k < DZ; ++k) m = fmaf(v[k], W_dec[k * DX + t], m);
    float mm = m * m;
    #pragma unroll
    for (int off = 32; off > 0; off >>= 1) mm += __shfl_down(mm, off, 64);
    if (t == 0) {
        munormb[j] = mm;
        float s = 0.0f;
        #pragma unroll
        for (int k = 0; k < DZ; ++k) s = fmaf(v[k], v[k], s);
        vnormb[j] = s + BIAS;
    }
}

// ---------- fused encoder + MFMA argmin + epilogue ----------
// One wave (64 threads) per block, 64 rows. No memory traffic in the hot
// loop except VGPR-resident B-fragments (streamed in 4 passes of 16
// coalesced 1KB loads) and conflict-free LDS vnorm reads. Min-tracking via
// packed keys: score biased positive (cin = vnorm+512), key =
// (bits & ~1023) | j  ->  v_and_or_b32 + v_min_u32 (2 ops/score).
__global__ __launch_bounds__(64, 2) void vq_encmin(
    const float* __restrict__ x, const float* __restrict__ W_enc,
    const float* __restrict__ b_enc, const float* __restrict__ W_dec,
    const float* __restrict__ b_dec, const float* __restrict__ vectors,
    const short* __restrict__ vbf, const float* __restrict__ vnormb,
    const float* __restrict__ munormb, unsigned* __restrict__ zp,
    unsigned short* __restrict__ bidx_out,
    float* __restrict__ recon_acc, float* __restrict__ commit_acc)
{
    __shared__ __attribute__((aligned(16))) short zbf[64 * 40];  // 80B rows (2-way-free pad)
    __shared__ float vnl[NB];
    __shared__ unsigned skey[64];
    const int t = threadIdx.x;
    const int r = blockIdx.x * 64 + t;

    // stage biased vnorm -> LDS (coalesced float4)
    #pragma unroll
    for (int i = 0; i < 4; ++i)
        ((float4*)vnl)[t + 64 * i] = ((const float4*)vnormb)[t + 64 * i];

    // ---- phase 1: fp32 encoder + y = x @ W_dec^T ----
    float znorm, xnorm, xb;
    float y[DZ];
    {
        float xr[DX];
        const float4* xp = reinterpret_cast<const float4*>(x + (size_t)r * DX);
        #pragma unroll
        for (int i = 0; i < DX / 4; ++i) {
            float4 v = xp[i];
            xr[4 * i + 0] = v.x; xr[4 * i + 1] = v.y;
            xr[4 * i + 2] = v.z; xr[4 * i + 3] = v.w;
        }
        float z[DZ];
        #pragma unroll
        for (int c = 0; c < DZ; ++c) z[c] = b_enc[c];
        #pragma unroll
        for (int k = 0; k < DX; ++k) {
            float xk = xr[k];
            #pragma unroll
            for (int c = 0; c < DZ; ++c) z[c] = fmaf(xk, W_enc[k * DZ + c], z[c]);
        }
        // y[c] = sum_k x[k] * W_dec[c*DX + k]   (wave-uniform s_loads)
        #pragma unroll
        for (int c = 0; c < DZ; ++c) {
            float acc = 0.0f;
            #pragma unroll
            for (int k = 0; k < DX; ++k) acc = fmaf(xr[k], W_dec[c * DX + k], acc);
            y[c] = acc;
        }
        xnorm = 0.0f; xb = 0.0f;
        #pragma unroll
        for (int k = 0; k < DX; ++k) {
            xnorm = fmaf(xr[k], xr[k], xnorm);
            xb    = fmaf(xr[k], b_dec[k], xb);
        }
        znorm = 0.0f;
        #pragma unroll
        for (int c = 0; c < DZ; ++c) znorm = fmaf(z[c], z[c], znorm);
        // z -> global as packed bf16 pairs (u32 stores, coalesced per cp)
        #pragma unroll
        for (int cp = 0; cp < DZ / 2; ++cp) {
            unsigned lo = (unsigned short)f2bf(z[2 * cp]);
            unsigned hi = (unsigned short)f2bf(z[2 * cp + 1]);
            zp[(size_t)cp * N_ROWS + r] = lo | (hi << 16);
        }
        // bf16(-2z) -> LDS for A-fragments
        #pragma unroll
        for (int c = 0; c < DZ; c += 2) {
            unsigned lo = (unsigned short)f2bf(-2.0f * z[c]);
            unsigned hi = (unsigned short)f2bf(-2.0f * z[c + 1]);
            *(unsigned*)&zbf[t * 40 + c] = lo | (hi << 16);
        }
    }
    __syncthreads();

    // ---- phase 2: MFMA argmin, B in VGPRs ----
    const int lm = t & 15;
    const int lq = t >> 4;

    shortx8 afrag[4];
    #pragma unroll
    for (int rt = 0; rt < 4; ++rt)
        afrag[rt] = *(const shortx8*)&zbf[(rt * 16 + lm) * 40 + lq * 8];

    unsigned key[16];
    #pragma unroll
    for (int k = 0; k < 16; ++k) key[k] = 0xFFFFFFFFu;

    for (int p = 0; p < 4; ++p) {
        shortx8 bb[16];
        #pragma unroll
        for (int jt = 0; jt < 16; ++jt)
            bb[jt] = *(const shortx8*)(vbf + (p * 256 + jt * 16 + lm) * DZ + lq * 8);
        #pragma unroll
        for (int jt = 0; jt < 16; ++jt) {
            const int jbase = p * 256 + jt * 16 + lm;
            float vn = vnl[jbase];
            floatx4 cin = {vn, vn, vn, vn};
            #pragma unroll
            for (int rt = 0; rt < 4; ++rt) {
                floatx4 acc = __builtin_amdgcn_mfma_f32_16x16x32_bf16(
                    afrag[rt], bb[jt], cin, 0, 0, 0);
                #pragma unroll
                for (int reg = 0; reg < 4; ++reg) {
                    unsigned u = __builtin_bit_cast(unsigned, acc[reg]);
                    unsigned pk = (u & 0xFFFFFC00u) | (unsigned)jbase;  // v_and_or_b32
                    int k = rt * 4 + reg;
                    key[k] = key[k] < pk ? key[k] : pk;                 // v_min_u32
                }
            }
        }
    }

    // cross-lane min over the 16 columns (lm bits); ties -> smaller j
    #pragma unroll
    for (int k = 0; k < 16; ++k) {
        unsigned kv = key[k];
        #pragma unroll
        for (int m = 1; m <= 8; m <<= 1) {
            unsigned ov = __shfl_xor(kv, m, 64);
            kv = ov < kv ? ov : kv;
        }
        if (lm == 0) {
            int rl = (k >> 2) * 16 + lq * 4 + (k & 3);   // row within block
            skey[rl] = kv;
        }
    }
    __syncthreads();

    // ---- phase 3: epilogue ----
    const unsigned kr = skey[t];
    const int bsel = (int)(kr & 1023u);
    const float score = __builtin_bit_cast(float, kr & 0xFFFFFC00u);
    float commit = znorm + (score - BIAS);       // ~ ||z - v_b||^2
    bidx_out[r] = (unsigned short)bsel;

    // recon = xnorm - 2*(y.v_b + xb) + ||mu_b||^2
    float yv = 0.0f;
    const float4* vp = reinterpret_cast<const float4*>(vectors + (size_t)bsel * DZ);
    #pragma unroll
    for (int i = 0; i < DZ / 4; ++i) {
        float4 v = vp[i];
        yv = fmaf(y[4 * i + 0], v.x, yv);
        yv = fmaf(y[4 * i + 1], v.y, yv);
        yv = fmaf(y[4 * i + 2], v.z, yv);
        yv = fmaf(y[4 * i + 3], v.w, yv);
    }
    float recon = xnorm - 2.0f * (yv + xb) + munormb[bsel];

    #pragma unroll
    for (int off = 32; off > 0; off >>= 1) {
        recon  += __shfl_down(recon, off, 64);
        commit += __shfl_down(commit, off, 64);
    }
    if (t == 0) {
        atomicAdd(recon_acc, recon);
        atomicAdd(commit_acc, commit);
    }
}

// Component-pair LDS histogram over packed bf16 z (LDS atomics only)
__global__ __launch_bounds__(256) void vq_hist2(
    const unsigned* __restrict__ zp, const unsigned short* __restrict__ bidx,
    float* __restrict__ hpart)
{
    const int ci    = blockIdx.x % 17;     // 0..15 = comp pair, 16 = counts
    const int chunk = blockIdx.x / 17;
    const int t = threadIdx.x;
    __shared__ float h[2 * NB];
    #pragma unroll
    for (int i = 0; i < 2 * NB / 256; ++i) h[t + 256 * i] = 0.0f;
    __syncthreads();

    const int base = chunk * HROWS;
    if (ci < 16) {
        const unsigned* zc = zp + (size_t)ci * N_ROWS;
        for (int i = 0; i < HROWS / 256; ++i) {
            int r = base + t + 256 * i;
            unsigned w = zc[r];
            int b = bidx[r];
            atomicAdd(&h[b],      __builtin_bit_cast(float, w << 16));
            atomicAdd(&h[b + NB], __builtin_bit_cast(float, w & 0xFFFF0000u));
        }
        __syncthreads();
        float* dst0 = hpart + (size_t)(chunk * 33 + 2 * ci) * NB;
        float* dst1 = dst0 + NB;
        #pragma unroll
        for (int i = 0; i < NB / 256; ++i) {
            dst0[t + 256 * i] = h[t + 256 * i];
            dst1[t + 256 * i] = h[NB + t + 256 * i];
        }
    } else {
        for (int i = 0; i < HROWS / 256; ++i) {
            int r = base + t + 256 * i;
            atomicAdd(&h[bidx[r]], 1.0f);
        }
        __syncthreads();
        float* dst = hpart + (size_t)(chunk * 33 + 32) * NB;
        #pragma unroll
        for (int i = 0; i < NB / 256; ++i) dst[t + 256 * i] = h[t + 256 * i];
    }
}

__global__ __launch_bounds__(1024) void vq_reduce(
    const float* __restrict__ hpart, float* __restrict__ counts,
    float* __restrict__ sum_z)
{
    const int c = blockIdx.x;     // 0..32
    const int b = threadIdx.x;    // 0..1023
    float acc = 0.0f;
    for (int chunk = 0; chunk < HCHUNKS; ++chunk)
        acc += hpart[(size_t)(chunk * 33 + c) * NB + b];
    if (c < 32) sum_z[(size_t)b * DZ + c] = acc;
    else        counts[b] = acc;
}

__global__ __launch_bounds__(1024) void vq_finalize(
    const float* __restrict__ vectors, const float* __restrict__ assignments,
    const float* __restrict__ noise, const float* __restrict__ counts,
    const float* __restrict__ sum_z, const float* __restrict__ recon_acc,
    const float* __restrict__ commit_acc, float* __restrict__ out)
{
    __shared__ float a[NB];
    __shared__ int nad[NB];
    __shared__ int ssum[NB];
    __shared__ float rv[NB];
    __shared__ int ri[NB];
    __shared__ int s_max_idx;
    const int t = threadIdx.x;

    const float cnt = counts[t];
    const float ba = cnt / NBF;                 // ba*N == cnt exactly (N=2^18)
    const float ae = 0.99f * assignments[t] + 0.01f * ba;
    a[t] = ae;
    const int dead = (ae * NBF < MIN_ASSIGN) ? 1 : 0;
    nad[t] = dead;
    ssum[t] = dead;
    rv[t] = ba; ri[t] = t;
    __syncthreads();

    for (int s = NB / 2; s > 0; s >>= 1) {
        if (t < s) {
            float ov = rv[t + s]; int oi = ri[t + s];
            if (ov > rv[t] || (ov == rv[t] && oi < ri[t])) { rv[t] = ov; ri[t] = oi; }
        }
        __syncthreads();
    }
    if (t == 0) s_max_idx = ri[0];
    __syncthreads();
    const int mx = s_max_idx;
    const float a0mx = a[mx];
    const int na_mx = nad[mx];

    // suffix count of dead codes (processing rank, scan runs high->low)
    for (int off = 1; off < NB; off <<= 1) {
        int v = (t + off < NB) ? ssum[t + off] : 0;
        __syncthreads();
        ssum[t] += v;
        __syncthreads();
    }
    const int K = ssum[0];

    float av = a[t];
    if (dead) av = ldexpf(a0mx, -ssum[t]);
    if (t == mx && K > 0) av = ldexpf(a0mx, -K);
    out[1 + NB * DZ + t] = av;

    const float mxn = (dead && t < mx && na_mx) ? 1.0f : 0.0f;
    #pragma unroll
    for (int c = 0; c < DZ; ++c) {
        float v2 = vectors[t * DZ + c];
        if (dead) v2 = vectors[mx * DZ + c] + mxn * noise[mx * DZ + c] + noise[t * DZ + c];
        float mean = (cnt == 0.0f) ? v2 : (sum_z[(size_t)t * DZ + c] / cnt);
        out[1 + t * DZ + c] = 0.99f * v2 + 0.01f * mean;
    }

    if (t == 0) {
        float recon = 0.5f * (recon_acc[0] / NBF) + 32.0f * 1.8378770664093453f;
        float commit = commit_acc[0] / (NBF * (float)DZ);
        out[0] = recon + 0.25f * commit;
    }
}

// ---------- fallback (round-1) path, used only if ws is too small ----------
__global__ __launch_bounds__(64) void vq_prep_fb(
    const float* __restrict__ vectors, const float* __restrict__ W_dec,
    const float* __restrict__ b_dec, float* __restrict__ vnorm,
    float* __restrict__ mu_table)
{
    const int j = blockIdx.x;
    const int t = threadIdx.x;
    __shared__ float v[DZ];
    if (t < DZ) v[t] = vectors[j * DZ + t];
    __syncthreads();
    float m = b_dec[t];
    #pragma unroll
    for (int k = 0; k < DZ; ++k) m = fmaf(v[k], W_dec[k * DX + t], m);
    mu_table[(size_t)j * DX + t] = m;
    if (t == 0) {
        float s = 0.0f;
        #pragma unroll
        for (int k = 0; k < DZ; ++k) s = fmaf(v[k], v[k], s);
        vnorm[j] = s;
    }
}

__global__ __launch_bounds__(256) void vq_main_atomic(
    const float* __restrict__ x, const float* __restrict__ W_enc,
    const float* __restrict__ b_enc, const float* __restrict__ vectors,
    const float* __restrict__ vnorm, const float* __restrict__ mu_table,
    float* __restrict__ counts, float* __restrict__ sum_z,
    float* __restrict__ recon_acc, float* __restrict__ commit_acc)
{
    const int r = blockIdx.x * 256 + threadIdx.x;
    float xr[DX];
    const float4* xp = reinterpret_cast<const float4*>(x + (size_t)r * DX);
    #pragma unroll
    for (int i = 0; i < DX / 4; ++i) {
        float4 v = xp[i];
        xr[4 * i + 0] = v.x; xr[4 * i + 1] = v.y;
        xr[4 * i + 2] = v.z; xr[4 * i + 3] = v.w;
    }
    float z[DZ];
    #pragma unroll
    for (int c = 0; c < DZ; ++c) z[c] = b_enc[c];
    #pragma unroll
    for (int k = 0; k < DX; ++k) {
        float xk = xr[k];
        #pragma unroll
        for (int c = 0; c < DZ; ++c) z[c] = fmaf(xk, W_enc[k * DZ + c], z[c]);
    }
    float znorm = 0.0f;
    #pragma unroll
    for (int c = 0; c < DZ; ++c) znorm = fmaf(z[c], z[c], znorm);
    float zm2[DZ];
    #pragma unroll
    for (int c = 0; c < DZ; ++c) zm2[c] = -2.0f * z[c];

    float best = 3.4e38f;
    int bidx = 0;
    for (int j = 0; j < NB; ++j) {
        const float* vj = vectors + j * DZ;
        float s0 = vnorm[j], s1 = 0.0f, s2 = 0.0f, s3 = 0.0f;
        #pragma unroll
        for (int c = 0; c < DZ; c += 4) {
            s0 = fmaf(zm2[c + 0], vj[c + 0], s0);
            s1 = fmaf(zm2[c + 1], vj[c + 1], s1);
            s2 = fmaf(zm2[c + 2], vj[c + 2], s2);
            s3 = fmaf(zm2[c + 3], vj[c + 3], s3);
        }
        float s = (s0 + s1) + (s2 + s3);
        if (s < best) { best = s; bidx = j; }
    }
    float commit_row = znorm + best;

    float rs = 0.0f;
    const float4* mup = reinterpret_cast<const float4*>(mu_table + (size_t)bidx * DX);
    #pragma unroll
    for (int i = 0; i < DX / 4; ++i) {
        float4 m = mup[i];
        float d0 = xr[4 * i + 0] - m.x; rs = fmaf(d0, d0, rs);
        float d1 = xr[4 * i + 1] - m.y; rs = fmaf(d1, d1, rs);
        float d2 = xr[4 * i + 2] - m.z; rs = fmaf(d2, d2, rs);
        float d3 = xr[4 * i + 3] - m.w; rs = fmaf(d3, d3, rs);
    }
    atomicAdd(&counts[bidx], 1.0f);
    #pragma unroll
    for (int c = 0; c < DZ; ++c)
        atomicAdd(&sum_z[(size_t)bidx * DZ + c], -0.5f * zm2[c]);
    #pragma unroll
    for (int off = 32; off > 0; off >>= 1) {
        rs += __shfl_down(rs, off, 64);
        commit_row += __shfl_down(commit_row, off, 64);
    }
    if ((threadIdx.x & 63) == 0) {
        atomicAdd(recon_acc, rs);
        atomicAdd(commit_acc, commit_row);
    }
}

__global__ __launch_bounds__(1024) void vq_finalize_fb(
    const float* __restrict__ vectors, const float* __restrict__ assignments,
    const float* __restrict__ noise, const float* __restrict__ counts,
    const float* __restrict__ sum_z, const float* __restrict__ recon_acc,
    const float* __restrict__ commit_acc, float* __restrict__ out)
{
    __shared__ float a[NB];
    __shared__ unsigned char na[NB];
    __shared__ float rv[NB];
    __shared__ int ri[NB];
    __shared__ int s_max_idx;
    const int t = threadIdx.x;

    const float cnt = counts[t];
    const float ba = cnt / NBF;
    const float ae = 0.99f * assignments[t] + 0.01f * ba;
    a[t] = ae;
    na[t] = (ae * NBF < MIN_ASSIGN) ? 1 : 0;
    rv[t] = ba; ri[t] = t;
    __syncthreads();
    for (int s = NB / 2; s > 0; s >>= 1) {
        if (t < s) {
            float ov = rv[t + s]; int oi = ri[t + s];
            if (ov > rv[t] || (ov == rv[t] && oi < ri[t])) { rv[t] = ov; ri[t] = oi; }
        }
        __syncthreads();
    }
    if (t == 0) s_max_idx = ri[0];
    __syncthreads();
    const int mx = s_max_idx;
    if (t == 0) {
        for (int i = NB - 1; i >= 0; --i) {
            if (na[i]) { float v = 0.5f * a[mx]; a[i] = v; a[mx] = v; }
        }
    }
    __syncthreads();
    out[1 + NB * DZ + t] = a[t];
    const bool dead = (na[t] != 0);
    #pragma unroll
    for (int c = 0; c < DZ; ++c) {
        float v2 = dead ? (vectors[mx * DZ + c] + noise[t * DZ + c])
                        : vectors[t * DZ + c];
        float mean = (cnt == 0.0f) ? v2 : (sum_z[(size_t)t * DZ + c] / cnt);
        out[1 + t * DZ + c] = 0.99f * v2 + 0.01f * mean;
    }
    if (t == 0) {
        float recon = 0.5f * (recon_acc[0] / NBF) + 32.0f * 1.8378770664093453f;
        float commit = commit_acc[0] / (NBF * (float)DZ);
        out[0] = recon + 0.25f * commit;
    }
}

extern "C" void kernel_launch(void* const* d_in, const int* in_sizes, int n_in,
                              void* d_out, int out_size, void* d_ws, size_t ws_size,
                              hipStream_t stream)
{
    const float* x           = (const float*)d_in[0];
    const float* W_enc       = (const float*)d_in[1];
    const float* b_enc       = (const float*)d_in[2];
    const float* vectors     = (const float*)d_in[3];
    const float* W_dec       = (const float*)d_in[4];
    const float* b_dec       = (const float*)d_in[5];
    const float* assignments = (const float*)d_in[6];
    const float* noise       = (const float*)d_in[7];
    float* out = (float*)d_out;
    float* ws  = (float*)d_ws;

    if (ws_size >= (size_t)WS_TOTAL * sizeof(float)) {
        vq_prep<<<NB, 64, 0, stream>>>(vectors, W_dec, b_dec,
            ws + WS_VNORMB, ws + WS_MUNORM, (short*)(ws + WS_VBF), ws + WS_RECON);
        vq_encmin<<<N_ROWS / 64, 64, 0, stream>>>(x, W_enc, b_enc, W_dec, b_dec,
            vectors, (const short*)(ws + WS_VBF), ws + WS_VNORMB, ws + WS_MUNORM,
            (unsigned*)(ws + WS_ZP), (unsigned short*)(ws + WS_BIDX),
            ws + WS_RECON, ws + WS_COMMIT);
        vq_hist2<<<17 * HCHUNKS, 256, 0, stream>>>(
            (const unsigned*)(ws + WS_ZP),
            (const unsigned short*)(ws + WS_BIDX), ws + WS_HPART);
        vq_reduce<<<33, 1024, 0, stream>>>(ws + WS_HPART,
            ws + WS_COUNTS, ws + WS_SUMZ);
        vq_finalize<<<1, NB, 0, stream>>>(vectors, assignments, noise,
            ws + WS_COUNTS, ws + WS_SUMZ, ws + WS_RECON, ws + WS_COMMIT, out);
    } else {
        zero_kernel<<<(FB_ZERO_N + 255) / 256, 256, 0, stream>>>(ws, FB_ZERO_N);
        vq_prep_fb<<<NB, 64, 0, stream>>>(vectors, W_dec, b_dec,
            ws + FB_VNORM, ws + FB_MUTAB);
        vq_main_atomic<<<N_ROWS / 256, 256, 0, stream>>>(x, W_enc, b_enc, vectors,
            ws + FB_VNORM, ws + FB_MUTAB, ws + FB_COUNTS, ws + FB_SUMZ,
            ws + FB_RECON, ws + FB_COMMIT);
        vq_finalize_fb<<<1, NB, 0, stream>>>(vectors, assignments, noise,
            ws + FB_COUNTS, ws + FB_SUMZ, ws + FB_RECON, ws + FB_COMMIT, out);
    }
}

// Round 7
// 382.133 us; speedup vs baseline: 4.7004x; 1.0471x over previous
//
#include <hip/hip_runtime.h>
#include <math.h>

// Problem constants (from reference setup_inputs)
#define N_ROWS 262144
#define DX 64
#define DZ 32
#define NB 1024
#define NBF 262144.0f
#define MIN_ASSIGN (0.1f / 1024.0f)
#define BIAS 512.0f

typedef short shortx8 __attribute__((ext_vector_type(8)));
typedef float floatx4 __attribute__((ext_vector_type(4)));
typedef float floatx2 __attribute__((ext_vector_type(2)));

// ---------- fast-path workspace layout (float offsets) ----------
#define WS_RECON  0
#define WS_COMMIT 1
#define WS_VNORMB 64                       // + 1024  (vnorm + 512 bias)
#define WS_MUTAB  1088                     // + 1024*64 = 65536
#define WS_VBF    66624                    // 1024*32 bf16 = 16384 floats
#define WS_ZP     83008                    // 16 * 262144 u32 (bf16-pair z) = 4194304
#define WS_BIDX   4277312                  // 262144 u16 = 131072 floats
#define WS_HPART  4408384                  // 33*32*1024 = 1081344
#define WS_COUNTS 5489728                  // + 1024
#define WS_SUMZ   5490752                  // + 32768
#define WS_TOTAL  5523520                  // floats (~22.1 MB)
#define HCHUNKS 32
#define HROWS  (N_ROWS / HCHUNKS)          // 8192 rows per chunk

// ---------- fallback (round-1) workspace layout ----------
#define FB_RECON  0
#define FB_COMMIT 1
#define FB_COUNTS 64
#define FB_SUMZ   1088
#define FB_VNORM  33856
#define FB_MUTAB  34880
#define FB_ZERO_N 33856

static __device__ __forceinline__ short f2bf(float f) {
    union { float f; unsigned u; } v; v.f = f;
    unsigned r = v.u + 0x7FFFu + ((v.u >> 16) & 1u);   // RNE
    return (short)(r >> 16);
}

__global__ __launch_bounds__(256) void zero_kernel(float* __restrict__ p, int n) {
    int i = blockIdx.x * 256 + threadIdx.x;
    if (i < n) p[i] = 0.0f;
}

// Per-bin: biased vnorm, mu_table row, bf16 codebook; block 0 zeroes accums.
__global__ __launch_bounds__(64) void vq_prep(
    const float* __restrict__ vectors, const float* __restrict__ W_dec,
    const float* __restrict__ b_dec, float* __restrict__ vnormb,
    float* __restrict__ mu_table, short* __restrict__ vbf,
    float* __restrict__ accums)
{
    const int j = blockIdx.x;
    const int t = threadIdx.x;
    if (j == 0 && t < 2) accums[t] = 0.0f;
    __shared__ float v[DZ];
    if (t < DZ) {
        float vv = vectors[j * DZ + t];
        v[t] = vv;
        vbf[j * DZ + t] = f2bf(vv);
    }
    __syncthreads();
    float m = b_dec[t];
    #pragma unroll
    for (int k = 0; k < DZ; ++k) m = fmaf(v[k], W_dec[k * DX + t], m);
    mu_table[(size_t)j * DX + t] = m;
    if (t == 0) {
        float s = 0.0f;
        #pragma unroll
        for (int k = 0; k < DZ; ++k) s = fmaf(v[k], v[k], s);
        vnormb[j] = s + BIAS;
    }
}

// ---------- fused encoder + MFMA argmin + epilogue (256-thread blocks) ----------
// 4 waves/block, __launch_bounds__(256,4) -> VGPR<=128, 4 blocks/CU (~50% occ).
// Encoder: fp32, packed float2 fma (v_pk_fma_f32), k-chunked (xr[32]).
// Argmin: A-fragments from LDS; B streamed through VGPRs 8 frags/pass from
// the 64 KB bf16 codebook (L2-resident, coalesced); packed-key min
// ((score&~1023)|j -> v_and_or_b32 + v_min_u32); shfl-xor column reduce.
// Epilogue: exact recon ||x - mu[b]||^2 via x re-read + mu gather.
__global__ __launch_bounds__(256, 4) void vq_encmin(
    const float* __restrict__ x, const float* __restrict__ W_enc,
    const float* __restrict__ b_enc, const short* __restrict__ vbf,
    const float* __restrict__ vnormb, const float* __restrict__ mutab,
    unsigned* __restrict__ zp, unsigned short* __restrict__ bidx_out,
    float* __restrict__ recon_acc, float* __restrict__ commit_acc)
{
    __shared__ __attribute__((aligned(16))) short zbf[256 * 40];  // 20480 B
    __shared__ float vnl[NB];                                     //  4096 B
    __shared__ unsigned skey[256];
    const int t = threadIdx.x;
    const int r = blockIdx.x * 256 + t;

    ((float4*)vnl)[t] = ((const float4*)vnormb)[t];   // stage biased vnorm

    // ---- phase 1: fp32 encoder (same per-component fma order as round 1) ----
    floatx2 z2[16];
    #pragma unroll
    for (int c2 = 0; c2 < 16; ++c2)
        z2[c2] = *(const floatx2*)&b_enc[2 * c2];
    #pragma unroll 1
    for (int h = 0; h < 2; ++h) {
        float xr[32];
        const float4* xp = (const float4*)(x + (size_t)r * DX + h * 32);
        #pragma unroll
        for (int i = 0; i < 8; ++i) {
            float4 vv = xp[i];
            xr[4 * i + 0] = vv.x; xr[4 * i + 1] = vv.y;
            xr[4 * i + 2] = vv.z; xr[4 * i + 3] = vv.w;
        }
        #pragma unroll
        for (int kk = 0; kk < 32; ++kk) {
            floatx2 xk2 = {xr[kk], xr[kk]};
            const floatx2* wrow = (const floatx2*)&W_enc[(h * 32 + kk) * DZ];
            #pragma unroll
            for (int c2 = 0; c2 < 16; ++c2)
                z2[c2] = __builtin_elementwise_fma(xk2, wrow[c2], z2[c2]);
        }
    }
    floatx2 zn2 = {0.0f, 0.0f};
    #pragma unroll
    for (int c2 = 0; c2 < 16; ++c2)
        zn2 = __builtin_elementwise_fma(z2[c2], z2[c2], zn2);
    const float znorm = zn2.x + zn2.y;

    #pragma unroll
    for (int c2 = 0; c2 < 16; ++c2) {
        unsigned lo = (unsigned short)f2bf(z2[c2].x);
        unsigned hi = (unsigned short)f2bf(z2[c2].y);
        zp[(size_t)c2 * N_ROWS + r] = lo | (hi << 16);
        unsigned l2 = (unsigned short)f2bf(-2.0f * z2[c2].x);
        unsigned h2 = (unsigned short)f2bf(-2.0f * z2[c2].y);
        *(unsigned*)&zbf[t * 40 + 2 * c2] = l2 | (h2 << 16);
    }
    __syncthreads();

    // ---- phase 2: MFMA argmin ----
    const int w = t >> 6, l = t & 63, lm = l & 15, lq = l >> 4;
    shortx8 afrag[4];
    #pragma unroll
    for (int rt = 0; rt < 4; ++rt)
        afrag[rt] = *(const shortx8*)&zbf[(w * 64 + rt * 16 + lm) * 40 + lq * 8];

    unsigned key[16];
    #pragma unroll
    for (int k = 0; k < 16; ++k) key[k] = 0xFFFFFFFFu;

    #pragma unroll 1
    for (int p = 0; p < 8; ++p) {
        shortx8 bb[8];
        #pragma unroll
        for (int jt = 0; jt < 8; ++jt)
            bb[jt] = *(const shortx8*)(vbf + (p * 128 + jt * 16 + lm) * DZ + lq * 8);
        #pragma unroll
        for (int jt = 0; jt < 8; ++jt) {
            const int jbase = p * 128 + jt * 16 + lm;
            float vn = vnl[jbase];
            floatx4 cin = {vn, vn, vn, vn};
            #pragma unroll
            for (int rt = 0; rt < 4; ++rt) {
                floatx4 acc = __builtin_amdgcn_mfma_f32_16x16x32_bf16(
                    afrag[rt], bb[jt], cin, 0, 0, 0);
                #pragma unroll
                for (int reg = 0; reg < 4; ++reg) {
                    unsigned u = __builtin_bit_cast(unsigned, acc[reg]);
                    unsigned pk = (u & 0xFFFFFC00u) | (unsigned)jbase;
                    int k = rt * 4 + reg;
                    key[k] = key[k] < pk ? key[k] : pk;
                }
            }
        }
    }
    #pragma unroll
    for (int k = 0; k < 16; ++k) {
        unsigned kv = key[k];
        #pragma unroll
        for (int m = 1; m <= 8; m <<= 1) {
            unsigned ov = __shfl_xor(kv, m, 64);
            kv = ov < kv ? ov : kv;
        }
        if (lm == 0)
            skey[w * 64 + (k >> 2) * 16 + lq * 4 + (k & 3)] = kv;
    }
    __syncthreads();

    // ---- phase 3: epilogue ----
    const unsigned kr = skey[t];
    const int bsel = (int)(kr & 1023u);
    const float score = __builtin_bit_cast(float, kr & 0xFFFFFC00u);
    float commit = znorm + (score - BIAS);
    bidx_out[r] = (unsigned short)bsel;

    float rs = 0.0f;
    const float4* xp2 = (const float4*)(x + (size_t)r * DX);
    const float4* mp  = (const float4*)(mutab + (size_t)bsel * DX);
    #pragma unroll
    for (int i = 0; i < DX / 4; ++i) {
        float4 xv = xp2[i];
        float4 m  = mp[i];
        float d0 = xv.x - m.x; rs = fmaf(d0, d0, rs);
        float d1 = xv.y - m.y; rs = fmaf(d1, d1, rs);
        float d2 = xv.z - m.z; rs = fmaf(d2, d2, rs);
        float d3 = xv.w - m.w; rs = fmaf(d3, d3, rs);
    }
    #pragma unroll
    for (int off = 32; off > 0; off >>= 1) {
        rs     += __shfl_down(rs, off, 64);
        commit += __shfl_down(commit, off, 64);
    }
    if (l == 0) {
        atomicAdd(recon_acc, rs);
        atomicAdd(commit_acc, commit);
    }
}

// Component-pair LDS histogram over packed bf16 z (LDS atomics only)
__global__ __launch_bounds__(256) void vq_hist2(
    const unsigned* __restrict__ zp, const unsigned short* __restrict__ bidx,
    float* __restrict__ hpart)
{
    const int ci    = blockIdx.x % 17;     // 0..15 = comp pair, 16 = counts
    const int chunk = blockIdx.x / 17;
    const int t = threadIdx.x;
    __shared__ float h[2 * NB];
    #pragma unroll
    for (int i = 0; i < 2 * NB / 256; ++i) h[t + 256 * i] = 0.0f;
    __syncthreads();

    const int base = chunk * HROWS;
    if (ci < 16) {
        const unsigned* zc = zp + (size_t)ci * N_ROWS;
        for (int i = 0; i < HROWS / 256; ++i) {
            int r = base + t + 256 * i;
            unsigned w = zc[r];
            int b = bidx[r];
            atomicAdd(&h[b],      __builtin_bit_cast(float, w << 16));
            atomicAdd(&h[b + NB], __builtin_bit_cast(float, w & 0xFFFF0000u));
        }
        __syncthreads();
        float* dst0 = hpart + (size_t)(chunk * 33 + 2 * ci) * NB;
        float* dst1 = dst0 + NB;
        #pragma unroll
        for (int i = 0; i < NB / 256; ++i) {
            dst0[t + 256 * i] = h[t + 256 * i];
            dst1[t + 256 * i] = h[NB + t + 256 * i];
        }
    } else {
        for (int i = 0; i < HROWS / 256; ++i) {
            int r = base + t + 256 * i;
            atomicAdd(&h[bidx[r]], 1.0f);
        }
        __syncthreads();
        float* dst = hpart + (size_t)(chunk * 33 + 32) * NB;
        #pragma unroll
        for (int i = 0; i < NB / 256; ++i) dst[t + 256 * i] = h[t + 256 * i];
    }
}

__global__ __launch_bounds__(1024) void vq_reduce(
    const float* __restrict__ hpart, float* __restrict__ counts,
    float* __restrict__ sum_z)
{
    const int c = blockIdx.x;     // 0..32
    const int b = threadIdx.x;    // 0..1023
    float acc = 0.0f;
    for (int chunk = 0; chunk < HCHUNKS; ++chunk)
        acc += hpart[(size_t)(chunk * 33 + c) * NB + b];
    if (c < 32) sum_z[(size_t)b * DZ + c] = acc;
    else        counts[b] = acc;
}

__global__ __launch_bounds__(1024) void vq_finalize(
    const float* __restrict__ vectors, const float* __restrict__ assignments,
    const float* __restrict__ noise, const float* __restrict__ counts,
    const float* __restrict__ sum_z, const float* __restrict__ recon_acc,
    const float* __restrict__ commit_acc, float* __restrict__ out)
{
    __shared__ float a[NB];
    __shared__ int nad[NB];
    __shared__ int ssum[NB];
    __shared__ float rv[NB];
    __shared__ int ri[NB];
    __shared__ int s_max_idx;
    const int t = threadIdx.x;

    const float cnt = counts[t];
    const float ba = cnt / NBF;                 // ba*N == cnt exactly (N=2^18)
    const float ae = 0.99f * assignments[t] + 0.01f * ba;
    a[t] = ae;
    const int dead = (ae * NBF < MIN_ASSIGN) ? 1 : 0;
    nad[t] = dead;
    ssum[t] = dead;
    rv[t] = ba; ri[t] = t;
    __syncthreads();

    for (int s = NB / 2; s > 0; s >>= 1) {
        if (t < s) {
            float ov = rv[t + s]; int oi = ri[t + s];
            if (ov > rv[t] || (ov == rv[t] && oi < ri[t])) { rv[t] = ov; ri[t] = oi; }
        }
        __syncthreads();
    }
    if (t == 0) s_max_idx = ri[0];
    __syncthreads();
    const int mx = s_max_idx;
    const float a0mx = a[mx];
    const int na_mx = nad[mx];

    // suffix count of dead codes (scan runs i = NB-1 .. 0)
    for (int off = 1; off < NB; off <<= 1) {
        int v = (t + off < NB) ? ssum[t + off] : 0;
        __syncthreads();
        ssum[t] += v;
        __syncthreads();
    }
    const int K = ssum[0];

    float av = a[t];
    if (dead) av = ldexpf(a0mx, -ssum[t]);
    if (t == mx && K > 0) av = ldexpf(a0mx, -K);
    out[1 + NB * DZ + t] = av;

    const float mxn = (dead && t < mx && na_mx) ? 1.0f : 0.0f;
    #pragma unroll
    for (int c = 0; c < DZ; ++c) {
        float v2 = vectors[t * DZ + c];
        if (dead) v2 = vectors[mx * DZ + c] + mxn * noise[mx * DZ + c] + noise[t * DZ + c];
        float mean = (cnt == 0.0f) ? v2 : (sum_z[(size_t)t * DZ + c] / cnt);
        out[1 + t * DZ + c] = 0.99f * v2 + 0.01f * mean;
    }

    if (t == 0) {
        float recon = 0.5f * (recon_acc[0] / NBF) + 32.0f * 1.8378770664093453f;
        float commit = commit_acc[0] / (NBF * (float)DZ);
        out[0] = recon + 0.25f * commit;
    }
}

// ---------- fallback (round-1) path, used only if ws is too small ----------
__global__ __launch_bounds__(64) void vq_prep_fb(
    const float* __restrict__ vectors, const float* __restrict__ W_dec,
    const float* __restrict__ b_dec, float* __restrict__ vnorm,
    float* __restrict__ mu_table)
{
    const int j = blockIdx.x;
    const int t = threadIdx.x;
    __shared__ float v[DZ];
    if (t < DZ) v[t] = vectors[j * DZ + t];
    __syncthreads();
    float m = b_dec[t];
    #pragma unroll
    for (int k = 0; k < DZ; ++k) m = fmaf(v[k], W_dec[k * DX + t], m);
    mu_table[(size_t)j * DX + t] = m;
    if (t == 0) {
        float s = 0.0f;
        #pragma unroll
        for (int k = 0; k < DZ; ++k) s = fmaf(v[k], v[k], s);
        vnorm[j] = s;
    }
}

__global__ __launch_bounds__(256) void vq_main_atomic(
    const float* __restrict__ x, const float* __restrict__ W_enc,
    const float* __restrict__ b_enc, const float* __restrict__ vectors,
    const float* __restrict__ vnorm, const float* __restrict__ mu_table,
    float* __restrict__ counts, float* __restrict__ sum_z,
    float* __restrict__ recon_acc, float* __restrict__ commit_acc)
{
    const int r = blockIdx.x * 256 + threadIdx.x;
    float xr[DX];
    const float4* xp = reinterpret_cast<const float4*>(x + (size_t)r * DX);
    #pragma unroll
    for (int i = 0; i < DX / 4; ++i) {
        float4 v = xp[i];
        xr[4 * i + 0] = v.x; xr[4 * i + 1] = v.y;
        xr[4 * i + 2] = v.z; xr[4 * i + 3] = v.w;
    }
    float z[DZ];
    #pragma unroll
    for (int c = 0; c < DZ; ++c) z[c] = b_enc[c];
    #pragma unroll
    for (int k = 0; k < DX; ++k) {
        float xk = xr[k];
        #pragma unroll
        for (int c = 0; c < DZ; ++c) z[c] = fmaf(xk, W_enc[k * DZ + c], z[c]);
    }
    float znorm = 0.0f;
    #pragma unroll
    for (int c = 0; c < DZ; ++c) znorm = fmaf(z[c], z[c], znorm);
    float zm2[DZ];
    #pragma unroll
    for (int c = 0; c < DZ; ++c) zm2[c] = -2.0f * z[c];

    float best = 3.4e38f;
    int bi = 0;
    for (int j = 0; j < NB; ++j) {
        const float* vj = vectors + j * DZ;
        float s0 = vnorm[j], s1 = 0.0f, s2 = 0.0f, s3 = 0.0f;
        #pragma unroll
        for (int c = 0; c < DZ; c += 4) {
            s0 = fmaf(zm2[c + 0], vj[c + 0], s0);
            s1 = fmaf(zm2[c + 1], vj[c + 1], s1);
            s2 = fmaf(zm2[c + 2], vj[c + 2], s2);
            s3 = fmaf(zm2[c + 3], vj[c + 3], s3);
        }
        float s = (s0 + s1) + (s2 + s3);
        if (s < best) { best = s; bi = j; }
    }
    float commit_row = znorm + best;

    float rs = 0.0f;
    const float4* mup = reinterpret_cast<const float4*>(mu_table + (size_t)bi * DX);
    #pragma unroll
    for (int i = 0; i < DX / 4; ++i) {
        float4 m = mup[i];
        float d0 = xr[4 * i + 0] - m.x; rs = fmaf(d0, d0, rs);
        float d1 = xr[4 * i + 1] - m.y; rs = fmaf(d1, d1, rs);
        float d2 = xr[4 * i + 2] - m.z; rs = fmaf(d2, d2, rs);
        float d3 = xr[4 * i + 3] - m.w; rs = fmaf(d3, d3, rs);
    }
    atomicAdd(&counts[bi], 1.0f);
    #pragma unroll
    for (int c = 0; c < DZ; ++c)
        atomicAdd(&sum_z[(size_t)bi * DZ + c], -0.5f * zm2[c]);
    #pragma unroll
    for (int off = 32; off > 0; off >>= 1) {
        rs += __shfl_down(rs, off, 64);
        commit_row += __shfl_down(commit_row, off, 64);
    }
    if ((threadIdx.x & 63) == 0) {
        atomicAdd(recon_acc, rs);
        atomicAdd(commit_acc, commit_row);
    }
}

__global__ __launch_bounds__(1024) void vq_finalize_fb(
    const float* __restrict__ vectors, const float* __restrict__ assignments,
    const float* __restrict__ noise, const float* __restrict__ counts,
    const float* __restrict__ sum_z, const float* __restrict__ recon_acc,
    const float* __restrict__ commit_acc, float* __restrict__ out)
{
    __shared__ float a[NB];
    __shared__ unsigned char na[NB];
    __shared__ float rv[NB];
    __shared__ int ri[NB];
    __shared__ int s_max_idx;
    const int t = threadIdx.x;

    const float cnt = counts[t];
    const float ba = cnt / NBF;
    const float ae = 0.99f * assignments[t] + 0.01f * ba;
    a[t] = ae;
    na[t] = (ae * NBF < MIN_ASSIGN) ? 1 : 0;
    rv[t] = ba; ri[t] = t;
    __syncthreads();
    for (int s = NB / 2; s > 0; s >>= 1) {
        if (t < s) {
            float ov = rv[t + s]; int oi = ri[t + s];
            if (ov > rv[t] || (ov == rv[t] && oi < ri[t])) { rv[t] = ov; ri[t] = oi; }
        }
        __syncthreads();
    }
    if (t == 0) s_max_idx = ri[0];
    __syncthreads();
    const int mx = s_max_idx;
    if (t == 0) {
        for (int i = NB - 1; i >= 0; --i) {
            if (na[i]) { float v = 0.5f * a[mx]; a[i] = v; a[mx] = v; }
        }
    }
    __syncthreads();
    out[1 + NB * DZ + t] = a[t];
    const bool dead = (na[t] != 0);
    #pragma unroll
    for (int c = 0; c < DZ; ++c) {
        float v2 = dead ? (vectors[mx * DZ + c] + noise[t * DZ + c])
                        : vectors[t * DZ + c];
        float mean = (cnt == 0.0f) ? v2 : (sum_z[(size_t)t * DZ + c] / cnt);
        out[1 + t * DZ + c] = 0.99f * v2 + 0.01f * mean;
    }
    if (t == 0) {
        float recon = 0.5f * (recon_acc[0] / NBF) + 32.0f * 1.8378770664093453f;
        float commit = commit_acc[0] / (NBF * (float)DZ);
        out[0] = recon + 0.25f * commit;
    }
}

extern "C" void kernel_launch(void* const* d_in, const int* in_sizes, int n_in,
                              void* d_out, int out_size, void* d_ws, size_t ws_size,
                              hipStream_t stream)
{
    const float* x           = (const float*)d_in[0];
    const float* W_enc       = (const float*)d_in[1];
    const float* b_enc       = (const float*)d_in[2];
    const float* vectors     = (const float*)d_in[3];
    const float* W_dec       = (const float*)d_in[4];
    const float* b_dec       = (const float*)d_in[5];
    const float* assignments = (const float*)d_in[6];
    const float* noise       = (const float*)d_in[7];
    float* out = (float*)d_out;
    float* ws  = (float*)d_ws;

    if (ws_size >= (size_t)WS_TOTAL * sizeof(float)) {
        vq_prep<<<NB, 64, 0, stream>>>(vectors, W_dec, b_dec,
            ws + WS_VNORMB, ws + WS_MUTAB, (short*)(ws + WS_VBF), ws + WS_RECON);
        vq_encmin<<<N_ROWS / 256, 256, 0, stream>>>(x, W_enc, b_enc,
            (const short*)(ws + WS_VBF), ws + WS_VNORMB, ws + WS_MUTAB,
            (unsigned*)(ws + WS_ZP), (unsigned short*)(ws + WS_BIDX),
            ws + WS_RECON, ws + WS_COMMIT);
        vq_hist2<<<17 * HCHUNKS, 256, 0, stream>>>(
            (const unsigned*)(ws + WS_ZP),
            (const unsigned short*)(ws + WS_BIDX), ws + WS_HPART);
        vq_reduce<<<33, 1024, 0, stream>>>(ws + WS_HPART,
            ws + WS_COUNTS, ws + WS_SUMZ);
        vq_finalize<<<1, NB, 0, stream>>>(vectors, assignments, noise,
            ws + WS_COUNTS, ws + WS_SUMZ, ws + WS_RECON, ws + WS_COMMIT, out);
    } else {
        zero_kernel<<<(FB_ZERO_N + 255) / 256, 256, 0, stream>>>(ws, FB_ZERO_N);
        vq_prep_fb<<<NB, 64, 0, stream>>>(vectors, W_dec, b_dec,
            ws + FB_VNORM, ws + FB_MUTAB);
        vq_main_atomic<<<N_ROWS / 256, 256, 0, stream>>>(x, W_enc, b_enc, vectors,
            ws + FB_VNORM, ws + FB_MUTAB, ws + FB_COUNTS, ws + FB_SUMZ,
            ws + FB_RECON, ws + FB_COMMIT);
        vq_finalize_fb<<<1, NB, 0, stream>>>(vectors, assignments, noise,
            ws + FB_COUNTS, ws + FB_SUMZ, ws + FB_RECON, ws + FB_COMMIT, out);
    }
}